// Round 10
// baseline (490.402 us; speedup 1.0000x reference)
//
#include <hip/hip_runtime.h>
#include <cstdint>
#include <cstddef>

// Problem constants (match reference)
#define NN 100000   // nodes
#define NE 1600000  // edges
#define IN_F 256    // input feats
#define HD 64       // hidden width
#define NC 16       // classes

// Bucketed-build constants
#define NT 391      // dst tiles of 256 nodes: tile = dst >> 8
#define NBLK 196    // count/fill blocks
#define EPB 8192    // edges per count/fill block (NBLK*EPB >= NE)
#define CM (NT * NBLK)   // counts elems = 76,636
#define SCB 75      // scan blocks: ceil(CM/1024)

// ---------------------------------------------------------------------------
// Workspace layout (bytes) — guaranteed budget 52,000,912 (proven R4-R7):
//   dinv   @ 0             NN floats                              400,000
//   A      @ 400,128       NN*64 floats (g1 -> g2 -> h3)       25,600,000
//          (tmp int2[NE] = 12.8 MB aliases A BEFORE k_gemm1 runs)
//   B      @ 26,000,128    NN*64 floats (agg1 -> agg2)         25,600,000
//          (counts/bsum/bpref alias B's head, dead after k_sort)
//   rowptr @ 51,600,128    (NN+1) ints                             400,004
//   [FULL only] pairsS @ 52,000,256  NE int2 (src|dl<<17, ew)  12,800,000
// Configs (by ws_size, constant per run -> graph-safe):
//   FULL (ws >= 64,800,912): row-sorted (src,ew) pairs in ws; 1-indirection.
//   DOUT (ws >= 52,000,912): row-sorted edge-ids in d_out; 2-indirection.
//   FALLBACK (else): atomic-scatter path.
//
// R13 changes (resubmitted — broker timeout, never measured):
//   R12 measured 479.9 µs; k_agg tops the profile: 71.3 µs x2,
//   FETCH 193.6 MB (≈8x g: per-XCD L2 replication of random gathers,
//   structural), 3.1 TB/s, occ 70%, VALU 23% — latency/MLP-bound:
//   4-unroll = ~4 outstanding g-loads/wave -> Little's-law cap ≈3.8 TB/s.
//   Fix: clamped 8-unroll (OOB slots: idx->p, weight->0; fmaf(0,g,acc)
//   exact) — 2x in-flight gathers AND no serial scalar tail (Poisson-16
//   degrees put ~half the rows in the old tail loop).
//   Edge order in acc unchanged -> numerics identical.
// No global atomics and no LDS *float* atomics anywhere on the main path.
// ---------------------------------------------------------------------------

// ---------------- tile-bucket build (LDS int atomics only) -----------------

__global__ __launch_bounds__(256) void k_count(const int* __restrict__ dstA,
                                               int* __restrict__ counts) {
    __shared__ int hist[NT];
    int tid = threadIdx.x;
    for (int t = tid; t < NT; t += 256) hist[t] = 0;
    __syncthreads();
    int base = blockIdx.x * EPB;
#pragma unroll
    for (int i = 0; i < 32; ++i) {
        int e = base + i * 256 + tid;
        if (e < NE) atomicAdd(&hist[dstA[e] >> 8], 1);  // native ds_add_u32
    }
    __syncthreads();
    for (int t = tid; t < NT; t += 256)
        counts[t * NBLK + blockIdx.x] = hist[t];
}

// exclusive scan of counts[CM] in place
__global__ __launch_bounds__(256) void k_scan1(int* __restrict__ c,
                                               int* __restrict__ bsum) {
    __shared__ int ss[256];
    int t = threadIdx.x;
    int base = blockIdx.x * 1024 + t * 4;
    int c0 = (base + 0 < CM) ? c[base + 0] : 0;
    int c1 = (base + 1 < CM) ? c[base + 1] : 0;
    int c2 = (base + 2 < CM) ? c[base + 2] : 0;
    int c3 = (base + 3 < CM) ? c[base + 3] : 0;
    int tsum = c0 + c1 + c2 + c3;
    ss[t] = tsum;
    __syncthreads();
    for (int off = 1; off < 256; off <<= 1) {
        int v = (t >= off) ? ss[t - off] : 0;
        __syncthreads();
        ss[t] += v;
        __syncthreads();
    }
    int excl = ss[t] - tsum;
    if (t == 255) bsum[blockIdx.x] = ss[255];
    if (base + 0 < CM) c[base + 0] = excl;
    if (base + 1 < CM) c[base + 1] = excl + c0;
    if (base + 2 < CM) c[base + 2] = excl + c0 + c1;
    if (base + 3 < CM) c[base + 3] = excl + c0 + c1 + c2;
}

__global__ __launch_bounds__(128) void k_scan2(const int* __restrict__ bsum,
                                               int* __restrict__ bpref) {
    __shared__ int ss[128];
    int t = threadIdx.x;
    int v = (t < SCB) ? bsum[t] : 0;
    ss[t] = v;
    __syncthreads();
    for (int off = 1; off < 128; off <<= 1) {
        int u = (t >= off) ? ss[t - off] : 0;
        __syncthreads();
        ss[t] += u;
        __syncthreads();
    }
    if (t < SCB) bpref[t] = ss[t] - v;
}

__global__ __launch_bounds__(256) void k_scan3(int* __restrict__ c,
                                               const int* __restrict__ bpref) {
    int i = blockIdx.x * 256 + threadIdx.x;
    if (i < CM) c[i] += bpref[i >> 10];
}

// fill tile buckets: tmp[pos] = FULL ? (src|dl<<17, ew) : (eid, dl)
template <bool FULL>
__global__ __launch_bounds__(256) void k_fill2(const int* __restrict__ srcA,
                                               const int* __restrict__ dstA,
                                               const float* __restrict__ ew,
                                               const int* __restrict__ counts,
                                               int2* __restrict__ tmp) {
    __shared__ int basel[NT];
    int tid = threadIdx.x;
    for (int t = tid; t < NT; t += 256) basel[t] = counts[t * NBLK + blockIdx.x];
    __syncthreads();
    int eb = blockIdx.x * EPB;
#pragma unroll
    for (int i = 0; i < 32; ++i) {
        int e = eb + i * 256 + tid;
        if (e < NE) {
            int d = dstA[e];
            int pos = atomicAdd(&basel[d >> 8], 1);  // native LDS int atomic
            if (FULL)
                tmp[pos] = make_int2(srcA[e] | ((d & 255) << 17),
                                     __float_as_int(ew[e]));
            else
                tmp[pos] = make_int2(e, d & 255);
        }
    }
}

// per-tile counting sort to row granularity. Writes rowptr + sorted payload.
// Fused degree/dinv tail — after the scatter, each thread sums its own
// row's edge weights (payload is L2-hot) and writes dinv[row] = rsqrt(1+sum).
template <bool FULL>
__global__ __launch_bounds__(256) void k_sort(const int* __restrict__ counts,
                                              const int2* __restrict__ tmp,
                                              int2* __restrict__ outP,
                                              int* __restrict__ outE,
                                              int* __restrict__ rowptr,
                                              const float* __restrict__ ew,
                                              float* __restrict__ dinv) {
    __shared__ int hist[256], ss[256], bases[256];
    int tid = threadIdx.x;
    int tile = blockIdx.x;
    int bs = counts[tile * NBLK];
    int be = (tile + 1 < NT) ? counts[(tile + 1) * NBLK] : NE;
    hist[tid] = 0;
    __syncthreads();
    for (int p = bs + tid; p < be; p += 256) {
        int dl = FULL ? ((tmp[p].x >> 17) & 255) : tmp[p].y;
        atomicAdd(&hist[dl], 1);  // native LDS int atomic
    }
    __syncthreads();
    int v = hist[tid];
    ss[tid] = v;
    __syncthreads();
    for (int off = 1; off < 256; off <<= 1) {
        int u = (tid >= off) ? ss[tid - off] : 0;
        __syncthreads();
        ss[tid] += u;
        __syncthreads();
    }
    int excl = ss[tid] - v;
    bases[tid] = bs + excl;
    int row = tile * 256 + tid;
    if (row < NN) rowptr[row] = bs + excl;
    if (tile == NT - 1 && tid == 0) rowptr[NN] = NE;
    __syncthreads();
    for (int p = bs + tid; p < be; p += 256) {
        int2 t2 = tmp[p];
        int dl = FULL ? ((t2.x >> 17) & 255) : t2.y;
        int pos = atomicAdd(&bases[dl], 1);
        if (FULL) outP[pos] = t2;
        else      outE[pos] = t2.x;
    }
    __syncthreads();  // global writes above visible to this block below
    if (row < NN) {
        int p0 = bs + excl, p1 = bs + excl + v;
        float s = 1.0f;  // self-loop weight
        for (int p = p0; p < p1; ++p)
            s += FULL ? __int_as_float(outP[p].y) : ew[outE[p]];
        dinv[row] = rsqrtf(s);
    }
}

// aggregate in g-space: g = dinv .* h (producers pre-scale rows).
// out[d] = dinv[d] * (g[d] + sum_e w_e * g[src_e])
//        = dinv[d]^2*h[d] + sum_e dinv[d]*w_e*dinv[s]*h[s]  (== reference)
// R13: clamped 8-unroll — 8 g-row gathers in flight per wave (was 4), no
// serial scalar tail. OOB slots clamp index to p and zero the weight:
// fmaf(0,g,acc) == acc exactly; real-edge order unchanged.
template <bool FULL>
__global__ __launch_bounds__(256) void k_agg(const int* __restrict__ rowptr,
                                             const int2* __restrict__ pairsS,
                                             const int* __restrict__ eid,
                                             const int* __restrict__ srcA,
                                             const float* __restrict__ ew,
                                             const float* __restrict__ dinv,
                                             const float* __restrict__ g,
                                             float* __restrict__ agg) {
    int row = blockIdx.x * 4 + (threadIdx.x >> 6);
    int lane = threadIdx.x & 63;
    if (row >= NN) return;
    int p = rowptr[row], pe = rowptr[row + 1];
    float di = dinv[row];
    float acc = g[(size_t)row * HD + lane];   // self term: g[d]
    for (; p < pe; p += 8) {
        float ws[8];
        float gs[8];
#pragma unroll
        for (int i = 0; i < 8; ++i) {
            bool live = (p + i < pe);
            int pi = live ? (p + i) : p;
            int s;
            float w;
            if (FULL) {
                int2 v = pairsS[pi];
                s = v.x & 0x1FFFF;
                w = __int_as_float(v.y);
            } else {
                int e = eid[pi];
                s = srcA[e];
                w = ew[e];
            }
            ws[i] = live ? w : 0.0f;
            gs[i] = g[(size_t)s * HD + lane];
        }
#pragma unroll
        for (int i = 0; i < 8; ++i)
            acc = fmaf(ws[i], gs[i], acc);
    }
    agg[(size_t)row * HD + lane] = di * acc;
}

// ---------------------------------------------------------------------------
// GEMM1: x[N,256] @ W1[256,64]. 64 rows/block (grid 1563 = 6.1 blocks/CU).
// Thread tile 4 rows x 4 cols (rs=tid>>4, cg=tid&15). K chunked by 32,
// both operands LDS-staged with dense loads. sX[32][68] k-major (pad 68:
// scatter-writes 2-way/free, b128 reads aligned).
// SCALE: multiply output row by dinv[row] (g-space).
// ---------------------------------------------------------------------------
template <bool SCALE>
__global__ __launch_bounds__(256, 6) void k_gemm1(const float* __restrict__ x,
                                                  const float* __restrict__ W1,
                                                  const float* __restrict__ dinv,
                                                  float* __restrict__ h0) {
    __shared__ float sX[32][68];     // [k][row], padded (8.7 KB)
    __shared__ float sW[32][64];     // [k][col] (8 KB)
    int tid = threadIdx.x;
    int rs  = tid >> 4;              // 0..15: row group (4 rows each)
    int cg  = tid & 15;              // 0..15: col group (4 cols each)
    int base = blockIdx.x * 64;

    // staging coords: srow = tid&31 (row within half), f4 = tid>>5 (0..7)
    int f4   = tid >> 5;
    int srow = tid & 31;

    float acc[4][4];
#pragma unroll
    for (int r = 0; r < 4; ++r)
#pragma unroll
        for (int c = 0; c < 4; ++c) acc[r][c] = 0.0f;

    for (int kc = 0; kc < IN_F; kc += 32) {
        __syncthreads();
        // stage W chunk: rows kc..kc+31 of W1, contiguous 8 KB
        {
            const float4* wsrc = (const float4*)(W1 + (size_t)kc * HD);
            float4* wdst = (float4*)&sW[0][0];
            wdst[tid]       = wsrc[tid];
            wdst[256 + tid] = wsrc[256 + tid];
        }
        // stage x chunk k-major: sX[k][row] = x[base+row][kc+k]
#pragma unroll
        for (int q = 0; q < 2; ++q) {
            int grow = q * 32 + srow;
            int growc = (base + grow < NN) ? (base + grow) : (NN - 1);
            float4 v = *(const float4*)(x + (size_t)growc * IN_F + kc + f4 * 4);
            sX[f4 * 4 + 0][grow] = v.x;
            sX[f4 * 4 + 1][grow] = v.y;
            sX[f4 * 4 + 2][grow] = v.z;
            sX[f4 * 4 + 3][grow] = v.w;
        }
        __syncthreads();
        // compute: 32 k-steps from LDS; per k: 2 ds_read_b128 + 16 FMA
#pragma unroll 4
        for (int k = 0; k < 32; ++k) {
            float xs[4];
            *(float4*)xs = *(const float4*)&sX[k][rs * 4];
            float wv[4];
            *(float4*)wv = *(const float4*)&sW[k][cg * 4];
#pragma unroll
            for (int r = 0; r < 4; ++r) {
                float xj = xs[r];
#pragma unroll
                for (int c = 0; c < 4; ++c) acc[r][c] = fmaf(xj, wv[c], acc[r][c]);
            }
        }
    }
#pragma unroll
    for (int r = 0; r < 4; ++r) {
        int row = base + rs * 4 + r;
        if (row >= NN) continue;
        float di = SCALE ? dinv[row] : 1.0f;
        *(float4*)(h0 + (size_t)row * HD + cg * 4) =
            make_float4(acc[r][0] * di, acc[r][1] * di,
                        acc[r][2] * di, acc[r][3] * di);
    }
}

// 64x64 GEMM with fused input bias+relu. 64-row tiles, 4 rows x 4 cols per
// thread (grid 1563, 1 B LDS/FMA). SCALEOUT: output row *= dinv[row].
template <bool BIASRELU, bool SCALEOUT>
__global__ __launch_bounds__(256, 6) void k_gemm64(const float* __restrict__ in,
                                                   const float* __restrict__ bin,
                                                   const float* __restrict__ W,
                                                   const float* __restrict__ bout,
                                                   const float* __restrict__ dinv,
                                                   float* __restrict__ outA) {
    __shared__ float sW[HD * HD];
    __shared__ float sBin[HD];
    int tid = threadIdx.x;
    int rs  = tid >> 4;
    int cg  = tid & 15;
    int base = blockIdx.x * 64;
    int rowc[4];
    bool rv[4];
#pragma unroll
    for (int r = 0; r < 4; ++r) {
        int row = base + rs + 16 * r;
        rv[r] = row < NN;
        rowc[r] = rv[r] ? row : (NN - 1);
    }
    {
        const float4* wsrc = (const float4*)W;
        float4* wdst = (float4*)sW;
#pragma unroll
        for (int q = 0; q < 4; ++q) wdst[q * 256 + tid] = wsrc[q * 256 + tid];
        if (tid < 16) ((float4*)sBin)[tid] = ((const float4*)bin)[tid];
    }
    __syncthreads();
    float acc[4][4];
#pragma unroll
    for (int r = 0; r < 4; ++r)
#pragma unroll
        for (int c = 0; c < 4; ++c) acc[r][c] = 0.0f;

    for (int k4 = 0; k4 < 16; ++k4) {
        float bs[4];
        *(float4*)bs = ((const float4*)sBin)[k4];
        float xs[4][4];
#pragma unroll
        for (int r = 0; r < 4; ++r)
            *(float4*)xs[r] = *(const float4*)(in + (size_t)rowc[r] * HD + k4 * 4);
#pragma unroll
        for (int j = 0; j < 4; ++j) {
            float wv[4];
            *(float4*)wv = *(const float4*)(sW + (k4 * 4 + j) * HD + cg * 4);
#pragma unroll
            for (int r = 0; r < 4; ++r) {
                float hv = fmaxf(xs[r][j] + bs[j], 0.0f);
#pragma unroll
                for (int c = 0; c < 4; ++c) acc[r][c] = fmaf(hv, wv[c], acc[r][c]);
            }
        }
    }
#pragma unroll
    for (int r = 0; r < 4; ++r) {
        if (!rv[r]) continue;
        float* ha = outA + (size_t)rowc[r] * HD + cg * 4;
        if (BIASRELU) {
            float bo[4];
            *(float4*)bo = *(const float4*)(bout + cg * 4);
            *(float4*)ha = make_float4(fmaxf(acc[r][0] + bo[0], 0.0f),
                                       fmaxf(acc[r][1] + bo[1], 0.0f),
                                       fmaxf(acc[r][2] + bo[2], 0.0f),
                                       fmaxf(acc[r][3] + bo[3], 0.0f));
        } else {
            float di = SCALEOUT ? dinv[rowc[r]] : 1.0f;
            *(float4*)ha = make_float4(acc[r][0] * di, acc[r][1] * di,
                                       acc[r][2] * di, acc[r][3] * di);
        }
    }
}

// --- fallback path kernels ---
__global__ __launch_bounds__(256) void k_init_fb(float* __restrict__ deg) {
    int i = blockIdx.x * 256 + threadIdx.x;
    if (i < NN) deg[i] = 1.0f;
}
__global__ __launch_bounds__(256) void k_edge_fb(const int* __restrict__ dst,
                                                 const float* __restrict__ ew,
                                                 float* __restrict__ deg) {
    int e = blockIdx.x * 256 + threadIdx.x;
    if (e < NE) atomicAdd(&deg[dst[e]], ew[e]);
}
__global__ __launch_bounds__(256) void k_dinv_fb(float* __restrict__ deg) {
    int i = blockIdx.x * 256 + threadIdx.x;
    if (i < NN) {
        float d = deg[i];
        deg[i] = d > 0.0f ? rsqrtf(d) : 0.0f;
    }
}
__global__ __launch_bounds__(256) void k_selfloop(const float* __restrict__ h,
                                                  const float* __restrict__ dinv,
                                                  float* __restrict__ agg) {
    int i = blockIdx.x * 256 + threadIdx.x;
    if (i >= NN * (HD / 4)) return;
    int row = i / (HD / 4);
    float di = dinv[row];
    float d2 = di * di;
    float4 v = ((const float4*)h)[i];
    ((float4*)agg)[i] = make_float4(v.x * d2, v.y * d2, v.z * d2, v.w * d2);
}
__global__ __launch_bounds__(256) void k_scatter(const int* __restrict__ src,
                                                 const int* __restrict__ dst,
                                                 const float* __restrict__ ew,
                                                 const float* __restrict__ dinv,
                                                 const float* __restrict__ h,
                                                 float* __restrict__ agg) {
    int e = blockIdx.x * 4 + (threadIdx.x >> 6);
    int lane = threadIdx.x & 63;
    if (e >= NE) return;
    int s = src[e];
    int d = dst[e];
    float nrm = dinv[s] * ew[e] * dinv[d];
    float v = h[(size_t)s * HD + lane] * nrm;
    atomicAdd(&agg[(size_t)d * HD + lane], v);
}

// logits = h3 @ Wm2 + bm2, softmax. Wm2 (4 KB) in LDS, 1 row/thread (grid 391).
__global__ __launch_bounds__(256, 4) void k_out(const float* __restrict__ h3,
                                                const float* __restrict__ Wm2,
                                                const float* __restrict__ bm2,
                                                float* __restrict__ out) {
    __shared__ float sW[HD * NC];
    int tid = threadIdx.x;
    ((float4*)sW)[tid] = ((const float4*)Wm2)[tid];
    __syncthreads();
    int row = blockIdx.x * 256 + tid;
    bool rv = row < NN;
    int rowc = rv ? row : (NN - 1);
    float acc[16];
#pragma unroll
    for (int c = 0; c < 16; ++c) acc[c] = 0.0f;

    for (int k4 = 0; k4 < 16; ++k4) {
        float xs[4];
        *(float4*)xs = *(const float4*)(h3 + (size_t)rowc * HD + k4 * 4);
#pragma unroll
        for (int j = 0; j < 4; ++j) {
            float wv[16];
            const float4* wr4 = (const float4*)(sW + (k4 * 4 + j) * NC);
#pragma unroll
            for (int q = 0; q < 4; ++q) ((float4*)wv)[q] = wr4[q];
            float xj = xs[j];
#pragma unroll
            for (int c = 0; c < 16; ++c) acc[c] = fmaf(xj, wv[c], acc[c]);
        }
    }
    if (!rv) return;
    float bm[16];
#pragma unroll
    for (int q = 0; q < 4; ++q) ((float4*)bm)[q] = ((const float4*)bm2)[q];
    float l[16];
#pragma unroll
    for (int c = 0; c < 16; ++c) l[c] = acc[c] + bm[c];
    float m = l[0];
#pragma unroll
    for (int c = 1; c < 16; ++c) m = fmaxf(m, l[c]);
    float ssum = 0.0f;
#pragma unroll
    for (int c = 0; c < 16; ++c) {
        l[c] = expf(l[c] - m);
        ssum += l[c];
    }
    float inv = 1.0f / ssum;
    float4* op = (float4*)(out + (size_t)rowc * NC);
#pragma unroll
    for (int q = 0; q < 4; ++q)
        op[q] = make_float4(l[q * 4] * inv, l[q * 4 + 1] * inv,
                            l[q * 4 + 2] * inv, l[q * 4 + 3] * inv);
}

extern "C" void kernel_launch(void* const* d_in, const int* in_sizes, int n_in,
                              void* d_out, int out_size, void* d_ws, size_t ws_size,
                              hipStream_t stream) {
    const float* x   = (const float*)d_in[0];
    const int*   ei  = (const int*)d_in[1];   // (2, E): [0,E)=src, [E,2E)=dst
    const float* ew  = (const float*)d_in[2];
    const float* W1  = (const float*)d_in[3];
    const float* b1  = (const float*)d_in[4];
    const float* W2  = (const float*)d_in[5];
    const float* b2  = (const float*)d_in[6];
    const float* Wm1 = (const float*)d_in[7];
    const float* bm1 = (const float*)d_in[8];
    const float* Wm2 = (const float*)d_in[9];
    const float* bm2 = (const float*)d_in[10];
    float* out = (float*)d_out;

    char* base = (char*)d_ws;
    float* dinv   = (float*)base;
    float* A      = (float*)(base + 400128);
    float* B      = (float*)(base + 26000128);
    int*   rowptr = (int*)(base + 51600128);        // (NN+1) ints
    int2*  pairsS = (int2*)(base + 52000256);       // FULL only
    // temporaries aliasing A / B before they're live:
    int2*  tmp    = (int2*)(base + 400128);         // in A, dead after k_sort
    int*   counts = (int*)(base + 26000128);        // in B, dead after k_sort
    int*   bsum   = (int*)(base + 26000128 + 306544);
    int*   bpref  = (int*)(base + 26000128 + 306944);

    const int* src = ei;
    const int* dst = ei + NE;

    const bool full  = ws_size >= (size_t)64800912;
    const bool douta = !full && ws_size >= (size_t)52000912;
    const int g_node = (NN + 255) / 256;   // 391
    const int g_g1   = (NN + 63) / 64;     // 1563
    const int g_g64  = (NN + 63) / 64;     // 1563
    const int g_agg  = (NN + 3) / 4;       // 25000
    const int g_red  = (NN * (HD / 4) + 255) / 256;  // 6250
    const int g_out  = (NN + 255) / 256;   // 391
    int* eid = (int*)d_out;

    if (full || douta) {
        // bucket build (LDS int atomics only)
        k_count<<<dim3(NBLK), dim3(256), 0, stream>>>(dst, counts);
        k_scan1<<<dim3(SCB), dim3(256), 0, stream>>>(counts, bsum);
        k_scan2<<<dim3(1), dim3(128), 0, stream>>>(bsum, bpref);
        k_scan3<<<dim3((CM + 255) / 256), dim3(256), 0, stream>>>(counts, bpref);
        if (full) {
            k_fill2<true><<<dim3(NBLK), dim3(256), 0, stream>>>(src, dst, ew, counts, tmp);
            k_sort<true><<<dim3(NT), dim3(256), 0, stream>>>(counts, tmp, pairsS, nullptr, rowptr, ew, dinv);
        } else {
            k_fill2<false><<<dim3(NBLK), dim3(256), 0, stream>>>(src, dst, ew, counts, tmp);
            k_sort<false><<<dim3(NT), dim3(256), 0, stream>>>(counts, tmp, nullptr, eid, rowptr, ew, dinv);
        }
        // layer 1: g1 = dinv .* (x @ W1)  (tmp dead -> A writable)
        k_gemm1<true><<<dim3(g_g1), dim3(256), 0, stream>>>(x, W1, dinv, A);
        if (full)
            k_agg<true><<<dim3(g_agg), dim3(256), 0, stream>>>(rowptr, pairsS, nullptr, src, ew, dinv, A, B);
        else
            k_agg<false><<<dim3(g_agg), dim3(256), 0, stream>>>(rowptr, nullptr, eid, src, ew, dinv, A, B);
        // layer 2: g2 = dinv .* (relu(agg1+b1) @ W2)
        k_gemm64<false, true><<<dim3(g_g64), dim3(256), 0, stream>>>(B, b1, W2, nullptr, dinv, A);
        if (full)
            k_agg<true><<<dim3(g_agg), dim3(256), 0, stream>>>(rowptr, pairsS, nullptr, src, ew, dinv, A, B);
        else
            k_agg<false><<<dim3(g_agg), dim3(256), 0, stream>>>(rowptr, nullptr, eid, src, ew, dinv, A, B);
        // MLP head + softmax (no scaling)
        k_gemm64<true, false><<<dim3(g_g64), dim3(256), 0, stream>>>(B, b2, Wm1, bm1, dinv, A);
        k_out<<<dim3(g_out), dim3(256), 0, stream>>>(A, Wm2, bm2, out);
    } else {
        // fallback: atomic scatter (h-space, unscaled producers)
        k_init_fb<<<dim3(g_node), dim3(256), 0, stream>>>(dinv);
        k_edge_fb<<<dim3(NE / 256), dim3(256), 0, stream>>>(dst, ew, dinv);
        k_dinv_fb<<<dim3(g_node), dim3(256), 0, stream>>>(dinv);
        k_gemm1<false><<<dim3(g_g1), dim3(256), 0, stream>>>(x, W1, dinv, A);
        k_selfloop<<<dim3(g_red), dim3(256), 0, stream>>>(A, dinv, B);
        k_scatter<<<dim3(NE / 4), dim3(256), 0, stream>>>(src, dst, ew, dinv, A, B);
        k_gemm64<false, false><<<dim3(g_g64), dim3(256), 0, stream>>>(B, b1, W2, nullptr, dinv, A);
        k_selfloop<<<dim3(g_red), dim3(256), 0, stream>>>(A, dinv, B);
        k_scatter<<<dim3(NE / 4), dim3(256), 0, stream>>>(src, dst, ew, dinv, A, B);
        k_gemm64<true, false><<<dim3(g_g64), dim3(256), 0, stream>>>(B, b2, Wm1, bm1, dinv, A);
        k_out<<<dim3(g_out), dim3(256), 0, stream>>>(A, Wm2, bm2, out);
    }
}

// Round 13
// 479.345 us; speedup vs baseline: 1.0231x; 1.0231x over previous
//
#include <hip/hip_runtime.h>
#include <cstdint>
#include <cstddef>

// Problem constants (match reference)
#define NN 100000   // nodes
#define NE 1600000  // edges
#define IN_F 256    // input feats
#define HD 64       // hidden width
#define NC 16       // classes

// Bucketed-build constants
#define NT 391      // dst tiles of 256 nodes: tile = dst >> 8
#define NBLK 196    // count/fill blocks
#define EPB 8192    // edges per count/fill block (NBLK*EPB >= NE)
#define CM (NT * NBLK)   // counts elems = 76,636
#define SCB 75      // scan blocks: ceil(CM/1024)

// ---------------------------------------------------------------------------
// Workspace layout (bytes) — guaranteed budget 52,000,912 (proven R4-R7):
//   dinv   @ 0             NN floats                              400,000
//   A      @ 400,128       NN*64 floats (g1 -> g2 -> h3)       25,600,000
//          (tmp int2[NE] = 12.8 MB aliases A BEFORE k_gemm1 runs)
//   B      @ 26,000,128    NN*64 floats (agg1 -> agg2)         25,600,000
//          (counts/bsum/bpref alias B's head, dead after k_sort)
//   rowptr @ 51,600,128    (NN+1) ints                             400,004
//   [FULL only] pairsS @ 52,000,256  NE int2 (src|dl<<17, ew)  12,800,000
// Configs (by ws_size, constant per run -> graph-safe):
//   FULL (ws >= 64,800,912): row-sorted (src,ew) pairs in ws; 1-indirection.
//   DOUT (ws >= 52,000,912): row-sorted edge-ids in d_out; 2-indirection.
//   FALLBACK (else): atomic-scatter path.
//
// R14 changes (resubmitted x2 — broker timeouts, never measured):
//   R13 post-mortem: clamped 8-unroll REGRESSED k_agg 71.3 -> 83.9 µs.
//   (1) clamp cndmasks doubled VALU cycles (23 -> 39% busy); (2) dead
//   slots issued real gathers (E[slots]=20 for 16 edges, +25% loads, BW
//   down to 2.67 TB/s); (3) VGPR=20 < the 16+ needed for ws/gs -> compiler
//   shrank liveness, never held 8 gathers in flight. Fix: UNCLAMPED 8-wide
//   main loop (p+8<=pe only: 8 payloads -> 8 gathers -> 8 FMAs, no
//   conditional VALU, no dead work) + R12's exact 4-wide + scalar tail.
//   Accumulation order = increasing p everywhere -> numerics identical.
// No global atomics and no LDS *float* atomics anywhere on the main path.
// ---------------------------------------------------------------------------

// ---------------- tile-bucket build (LDS int atomics only) -----------------

__global__ __launch_bounds__(256) void k_count(const int* __restrict__ dstA,
                                               int* __restrict__ counts) {
    __shared__ int hist[NT];
    int tid = threadIdx.x;
    for (int t = tid; t < NT; t += 256) hist[t] = 0;
    __syncthreads();
    int base = blockIdx.x * EPB;
#pragma unroll
    for (int i = 0; i < 32; ++i) {
        int e = base + i * 256 + tid;
        if (e < NE) atomicAdd(&hist[dstA[e] >> 8], 1);  // native ds_add_u32
    }
    __syncthreads();
    for (int t = tid; t < NT; t += 256)
        counts[t * NBLK + blockIdx.x] = hist[t];
}

// exclusive scan of counts[CM] in place
__global__ __launch_bounds__(256) void k_scan1(int* __restrict__ c,
                                               int* __restrict__ bsum) {
    __shared__ int ss[256];
    int t = threadIdx.x;
    int base = blockIdx.x * 1024 + t * 4;
    int c0 = (base + 0 < CM) ? c[base + 0] : 0;
    int c1 = (base + 1 < CM) ? c[base + 1] : 0;
    int c2 = (base + 2 < CM) ? c[base + 2] : 0;
    int c3 = (base + 3 < CM) ? c[base + 3] : 0;
    int tsum = c0 + c1 + c2 + c3;
    ss[t] = tsum;
    __syncthreads();
    for (int off = 1; off < 256; off <<= 1) {
        int v = (t >= off) ? ss[t - off] : 0;
        __syncthreads();
        ss[t] += v;
        __syncthreads();
    }
    int excl = ss[t] - tsum;
    if (t == 255) bsum[blockIdx.x] = ss[255];
    if (base + 0 < CM) c[base + 0] = excl;
    if (base + 1 < CM) c[base + 1] = excl + c0;
    if (base + 2 < CM) c[base + 2] = excl + c0 + c1;
    if (base + 3 < CM) c[base + 3] = excl + c0 + c1 + c2;
}

__global__ __launch_bounds__(128) void k_scan2(const int* __restrict__ bsum,
                                               int* __restrict__ bpref) {
    __shared__ int ss[128];
    int t = threadIdx.x;
    int v = (t < SCB) ? bsum[t] : 0;
    ss[t] = v;
    __syncthreads();
    for (int off = 1; off < 128; off <<= 1) {
        int u = (t >= off) ? ss[t - off] : 0;
        __syncthreads();
        ss[t] += u;
        __syncthreads();
    }
    if (t < SCB) bpref[t] = ss[t] - v;
}

__global__ __launch_bounds__(256) void k_scan3(int* __restrict__ c,
                                               const int* __restrict__ bpref) {
    int i = blockIdx.x * 256 + threadIdx.x;
    if (i < CM) c[i] += bpref[i >> 10];
}

// fill tile buckets: tmp[pos] = FULL ? (src|dl<<17, ew) : (eid, dl)
template <bool FULL>
__global__ __launch_bounds__(256) void k_fill2(const int* __restrict__ srcA,
                                               const int* __restrict__ dstA,
                                               const float* __restrict__ ew,
                                               const int* __restrict__ counts,
                                               int2* __restrict__ tmp) {
    __shared__ int basel[NT];
    int tid = threadIdx.x;
    for (int t = tid; t < NT; t += 256) basel[t] = counts[t * NBLK + blockIdx.x];
    __syncthreads();
    int eb = blockIdx.x * EPB;
#pragma unroll
    for (int i = 0; i < 32; ++i) {
        int e = eb + i * 256 + tid;
        if (e < NE) {
            int d = dstA[e];
            int pos = atomicAdd(&basel[d >> 8], 1);  // native LDS int atomic
            if (FULL)
                tmp[pos] = make_int2(srcA[e] | ((d & 255) << 17),
                                     __float_as_int(ew[e]));
            else
                tmp[pos] = make_int2(e, d & 255);
        }
    }
}

// per-tile counting sort to row granularity. Writes rowptr + sorted payload.
// Fused degree/dinv tail — after the scatter, each thread sums its own
// row's edge weights (payload is L2-hot) and writes dinv[row] = rsqrt(1+sum).
template <bool FULL>
__global__ __launch_bounds__(256) void k_sort(const int* __restrict__ counts,
                                              const int2* __restrict__ tmp,
                                              int2* __restrict__ outP,
                                              int* __restrict__ outE,
                                              int* __restrict__ rowptr,
                                              const float* __restrict__ ew,
                                              float* __restrict__ dinv) {
    __shared__ int hist[256], ss[256], bases[256];
    int tid = threadIdx.x;
    int tile = blockIdx.x;
    int bs = counts[tile * NBLK];
    int be = (tile + 1 < NT) ? counts[(tile + 1) * NBLK] : NE;
    hist[tid] = 0;
    __syncthreads();
    for (int p = bs + tid; p < be; p += 256) {
        int dl = FULL ? ((tmp[p].x >> 17) & 255) : tmp[p].y;
        atomicAdd(&hist[dl], 1);  // native LDS int atomic
    }
    __syncthreads();
    int v = hist[tid];
    ss[tid] = v;
    __syncthreads();
    for (int off = 1; off < 256; off <<= 1) {
        int u = (tid >= off) ? ss[tid - off] : 0;
        __syncthreads();
        ss[tid] += u;
        __syncthreads();
    }
    int excl = ss[tid] - v;
    bases[tid] = bs + excl;
    int row = tile * 256 + tid;
    if (row < NN) rowptr[row] = bs + excl;
    if (tile == NT - 1 && tid == 0) rowptr[NN] = NE;
    __syncthreads();
    for (int p = bs + tid; p < be; p += 256) {
        int2 t2 = tmp[p];
        int dl = FULL ? ((t2.x >> 17) & 255) : t2.y;
        int pos = atomicAdd(&bases[dl], 1);
        if (FULL) outP[pos] = t2;
        else      outE[pos] = t2.x;
    }
    __syncthreads();  // global writes above visible to this block below
    if (row < NN) {
        int p0 = bs + excl, p1 = bs + excl + v;
        float s = 1.0f;  // self-loop weight
        for (int p = p0; p < p1; ++p)
            s += FULL ? __int_as_float(outP[p].y) : ew[outE[p]];
        dinv[row] = rsqrtf(s);
    }
}

// aggregate in g-space: g = dinv .* h (producers pre-scale rows).
// out[d] = dinv[d] * (g[d] + sum_e w_e * g[src_e])
//        = dinv[d]^2*h[d] + sum_e dinv[d]*w_e*dinv[s]*h[s]  (== reference)
// R14: unclamped 8-wide main loop (8 payloads -> 8 gathers -> 8 FMAs, no
// conditional VALU, no dead gathers) + R12's 4-wide + scalar tail.
template <bool FULL>
__global__ __launch_bounds__(256) void k_agg(const int* __restrict__ rowptr,
                                             const int2* __restrict__ pairsS,
                                             const int* __restrict__ eid,
                                             const int* __restrict__ srcA,
                                             const float* __restrict__ ew,
                                             const float* __restrict__ dinv,
                                             const float* __restrict__ g,
                                             float* __restrict__ agg) {
    int row = blockIdx.x * 4 + (threadIdx.x >> 6);
    int lane = threadIdx.x & 63;
    if (row >= NN) return;
    int p = rowptr[row], pe = rowptr[row + 1];
    float di = dinv[row];
    float acc = g[(size_t)row * HD + lane];   // self term: g[d]
    // 8-wide main loop: full groups only — no clamp VALU, no dead loads.
    for (; p + 8 <= pe; p += 8) {
        int   sv[8];
        float wv[8];
        if (FULL) {
#pragma unroll
            for (int i = 0; i < 8; ++i) {
                int2 v = pairsS[p + i];
                sv[i] = v.x & 0x1FFFF;
                wv[i] = __int_as_float(v.y);
            }
        } else {
            int ev[8];
#pragma unroll
            for (int i = 0; i < 8; ++i) ev[i] = eid[p + i];
#pragma unroll
            for (int i = 0; i < 8; ++i) { sv[i] = srcA[ev[i]]; wv[i] = ew[ev[i]]; }
        }
        float gs[8];
#pragma unroll
        for (int i = 0; i < 8; ++i)
            gs[i] = g[(size_t)sv[i] * HD + lane];
#pragma unroll
        for (int i = 0; i < 8; ++i)
            acc = fmaf(wv[i], gs[i], acc);
    }
    // 4-wide (R12-proven)
    for (; p + 4 <= pe; p += 4) {
        if (FULL) {
            int2 v0 = pairsS[p], v1 = pairsS[p + 1],
                 v2 = pairsS[p + 2], v3 = pairsS[p + 3];
            int s0 = v0.x & 0x1FFFF, s1 = v1.x & 0x1FFFF,
                s2 = v2.x & 0x1FFFF, s3 = v3.x & 0x1FFFF;
            float g0 = g[(size_t)s0 * HD + lane];
            float g1 = g[(size_t)s1 * HD + lane];
            float g2 = g[(size_t)s2 * HD + lane];
            float g3 = g[(size_t)s3 * HD + lane];
            acc = fmaf(__int_as_float(v0.y), g0, acc);
            acc = fmaf(__int_as_float(v1.y), g1, acc);
            acc = fmaf(__int_as_float(v2.y), g2, acc);
            acc = fmaf(__int_as_float(v3.y), g3, acc);
        } else {
            int e0 = eid[p], e1 = eid[p + 1], e2 = eid[p + 2], e3 = eid[p + 3];
            int s0 = srcA[e0], s1 = srcA[e1], s2 = srcA[e2], s3 = srcA[e3];
            float g0 = g[(size_t)s0 * HD + lane];
            float g1 = g[(size_t)s1 * HD + lane];
            float g2 = g[(size_t)s2 * HD + lane];
            float g3 = g[(size_t)s3 * HD + lane];
            acc = fmaf(ew[e0], g0, acc);
            acc = fmaf(ew[e1], g1, acc);
            acc = fmaf(ew[e2], g2, acc);
            acc = fmaf(ew[e3], g3, acc);
        }
    }
    // scalar tail
    for (; p < pe; ++p) {
        if (FULL) {
            int2 v = pairsS[p];
            acc = fmaf(__int_as_float(v.y),
                       g[(size_t)(v.x & 0x1FFFF) * HD + lane], acc);
        } else {
            int e = eid[p];
            acc = fmaf(ew[e], g[(size_t)srcA[e] * HD + lane], acc);
        }
    }
    agg[(size_t)row * HD + lane] = di * acc;
}

// ---------------------------------------------------------------------------
// GEMM1: x[N,256] @ W1[256,64]. 64 rows/block (grid 1563 = 6.1 blocks/CU).
// Thread tile 4 rows x 4 cols (rs=tid>>4, cg=tid&15). K chunked by 32,
// both operands LDS-staged with dense loads. sX[32][68] k-major (pad 68:
// scatter-writes 2-way/free, b128 reads aligned).
// SCALE: multiply output row by dinv[row] (g-space).
// ---------------------------------------------------------------------------
template <bool SCALE>
__global__ __launch_bounds__(256, 6) void k_gemm1(const float* __restrict__ x,
                                                  const float* __restrict__ W1,
                                                  const float* __restrict__ dinv,
                                                  float* __restrict__ h0) {
    __shared__ float sX[32][68];     // [k][row], padded (8.7 KB)
    __shared__ float sW[32][64];     // [k][col] (8 KB)
    int tid = threadIdx.x;
    int rs  = tid >> 4;              // 0..15: row group (4 rows each)
    int cg  = tid & 15;              // 0..15: col group (4 cols each)
    int base = blockIdx.x * 64;

    // staging coords: srow = tid&31 (row within half), f4 = tid>>5 (0..7)
    int f4   = tid >> 5;
    int srow = tid & 31;

    float acc[4][4];
#pragma unroll
    for (int r = 0; r < 4; ++r)
#pragma unroll
        for (int c = 0; c < 4; ++c) acc[r][c] = 0.0f;

    for (int kc = 0; kc < IN_F; kc += 32) {
        __syncthreads();
        // stage W chunk: rows kc..kc+31 of W1, contiguous 8 KB
        {
            const float4* wsrc = (const float4*)(W1 + (size_t)kc * HD);
            float4* wdst = (float4*)&sW[0][0];
            wdst[tid]       = wsrc[tid];
            wdst[256 + tid] = wsrc[256 + tid];
        }
        // stage x chunk k-major: sX[k][row] = x[base+row][kc+k]
#pragma unroll
        for (int q = 0; q < 2; ++q) {
            int grow = q * 32 + srow;
            int growc = (base + grow < NN) ? (base + grow) : (NN - 1);
            float4 v = *(const float4*)(x + (size_t)growc * IN_F + kc + f4 * 4);
            sX[f4 * 4 + 0][grow] = v.x;
            sX[f4 * 4 + 1][grow] = v.y;
            sX[f4 * 4 + 2][grow] = v.z;
            sX[f4 * 4 + 3][grow] = v.w;
        }
        __syncthreads();
        // compute: 32 k-steps from LDS; per k: 2 ds_read_b128 + 16 FMA
#pragma unroll 4
        for (int k = 0; k < 32; ++k) {
            float xs[4];
            *(float4*)xs = *(const float4*)&sX[k][rs * 4];
            float wv[4];
            *(float4*)wv = *(const float4*)&sW[k][cg * 4];
#pragma unroll
            for (int r = 0; r < 4; ++r) {
                float xj = xs[r];
#pragma unroll
                for (int c = 0; c < 4; ++c) acc[r][c] = fmaf(xj, wv[c], acc[r][c]);
            }
        }
    }
#pragma unroll
    for (int r = 0; r < 4; ++r) {
        int row = base + rs * 4 + r;
        if (row >= NN) continue;
        float di = SCALE ? dinv[row] : 1.0f;
        *(float4*)(h0 + (size_t)row * HD + cg * 4) =
            make_float4(acc[r][0] * di, acc[r][1] * di,
                        acc[r][2] * di, acc[r][3] * di);
    }
}

// 64x64 GEMM with fused input bias+relu. 64-row tiles, 4 rows x 4 cols per
// thread (grid 1563, 1 B LDS/FMA). SCALEOUT: output row *= dinv[row].
template <bool BIASRELU, bool SCALEOUT>
__global__ __launch_bounds__(256, 6) void k_gemm64(const float* __restrict__ in,
                                                   const float* __restrict__ bin,
                                                   const float* __restrict__ W,
                                                   const float* __restrict__ bout,
                                                   const float* __restrict__ dinv,
                                                   float* __restrict__ outA) {
    __shared__ float sW[HD * HD];
    __shared__ float sBin[HD];
    int tid = threadIdx.x;
    int rs  = tid >> 4;
    int cg  = tid & 15;
    int base = blockIdx.x * 64;
    int rowc[4];
    bool rv[4];
#pragma unroll
    for (int r = 0; r < 4; ++r) {
        int row = base + rs + 16 * r;
        rv[r] = row < NN;
        rowc[r] = rv[r] ? row : (NN - 1);
    }
    {
        const float4* wsrc = (const float4*)W;
        float4* wdst = (float4*)sW;
#pragma unroll
        for (int q = 0; q < 4; ++q) wdst[q * 256 + tid] = wsrc[q * 256 + tid];
        if (tid < 16) ((float4*)sBin)[tid] = ((const float4*)bin)[tid];
    }
    __syncthreads();
    float acc[4][4];
#pragma unroll
    for (int r = 0; r < 4; ++r)
#pragma unroll
        for (int c = 0; c < 4; ++c) acc[r][c] = 0.0f;

    for (int k4 = 0; k4 < 16; ++k4) {
        float bs[4];
        *(float4*)bs = ((const float4*)sBin)[k4];
        float xs[4][4];
#pragma unroll
        for (int r = 0; r < 4; ++r)
            *(float4*)xs[r] = *(const float4*)(in + (size_t)rowc[r] * HD + k4 * 4);
#pragma unroll
        for (int j = 0; j < 4; ++j) {
            float wv[4];
            *(float4*)wv = *(const float4*)(sW + (k4 * 4 + j) * HD + cg * 4);
#pragma unroll
            for (int r = 0; r < 4; ++r) {
                float hv = fmaxf(xs[r][j] + bs[j], 0.0f);
#pragma unroll
                for (int c = 0; c < 4; ++c) acc[r][c] = fmaf(hv, wv[c], acc[r][c]);
            }
        }
    }
#pragma unroll
    for (int r = 0; r < 4; ++r) {
        if (!rv[r]) continue;
        float* ha = outA + (size_t)rowc[r] * HD + cg * 4;
        if (BIASRELU) {
            float bo[4];
            *(float4*)bo = *(const float4*)(bout + cg * 4);
            *(float4*)ha = make_float4(fmaxf(acc[r][0] + bo[0], 0.0f),
                                       fmaxf(acc[r][1] + bo[1], 0.0f),
                                       fmaxf(acc[r][2] + bo[2], 0.0f),
                                       fmaxf(acc[r][3] + bo[3], 0.0f));
        } else {
            float di = SCALEOUT ? dinv[rowc[r]] : 1.0f;
            *(float4*)ha = make_float4(acc[r][0] * di, acc[r][1] * di,
                                       acc[r][2] * di, acc[r][3] * di);
        }
    }
}

// --- fallback path kernels ---
__global__ __launch_bounds__(256) void k_init_fb(float* __restrict__ deg) {
    int i = blockIdx.x * 256 + threadIdx.x;
    if (i < NN) deg[i] = 1.0f;
}
__global__ __launch_bounds__(256) void k_edge_fb(const int* __restrict__ dst,
                                                 const float* __restrict__ ew,
                                                 float* __restrict__ deg) {
    int e = blockIdx.x * 256 + threadIdx.x;
    if (e < NE) atomicAdd(&deg[dst[e]], ew[e]);
}
__global__ __launch_bounds__(256) void k_dinv_fb(float* __restrict__ deg) {
    int i = blockIdx.x * 256 + threadIdx.x;
    if (i < NN) {
        float d = deg[i];
        deg[i] = d > 0.0f ? rsqrtf(d) : 0.0f;
    }
}
__global__ __launch_bounds__(256) void k_selfloop(const float* __restrict__ h,
                                                  const float* __restrict__ dinv,
                                                  float* __restrict__ agg) {
    int i = blockIdx.x * 256 + threadIdx.x;
    if (i >= NN * (HD / 4)) return;
    int row = i / (HD / 4);
    float di = dinv[row];
    float d2 = di * di;
    float4 v = ((const float4*)h)[i];
    ((float4*)agg)[i] = make_float4(v.x * d2, v.y * d2, v.z * d2, v.w * d2);
}
__global__ __launch_bounds__(256) void k_scatter(const int* __restrict__ src,
                                                 const int* __restrict__ dst,
                                                 const float* __restrict__ ew,
                                                 const float* __restrict__ dinv,
                                                 const float* __restrict__ h,
                                                 float* __restrict__ agg) {
    int e = blockIdx.x * 4 + (threadIdx.x >> 6);
    int lane = threadIdx.x & 63;
    if (e >= NE) return;
    int s = src[e];
    int d = dst[e];
    float nrm = dinv[s] * ew[e] * dinv[d];
    float v = h[(size_t)s * HD + lane] * nrm;
    atomicAdd(&agg[(size_t)d * HD + lane], v);
}

// logits = h3 @ Wm2 + bm2, softmax. Wm2 (4 KB) in LDS, 1 row/thread (grid 391).
__global__ __launch_bounds__(256, 4) void k_out(const float* __restrict__ h3,
                                                const float* __restrict__ Wm2,
                                                const float* __restrict__ bm2,
                                                float* __restrict__ out) {
    __shared__ float sW[HD * NC];
    int tid = threadIdx.x;
    ((float4*)sW)[tid] = ((const float4*)Wm2)[tid];
    __syncthreads();
    int row = blockIdx.x * 256 + tid;
    bool rv = row < NN;
    int rowc = rv ? row : (NN - 1);
    float acc[16];
#pragma unroll
    for (int c = 0; c < 16; ++c) acc[c] = 0.0f;

    for (int k4 = 0; k4 < 16; ++k4) {
        float xs[4];
        *(float4*)xs = *(const float4*)(h3 + (size_t)rowc * HD + k4 * 4);
#pragma unroll
        for (int j = 0; j < 4; ++j) {
            float wv[16];
            const float4* wr4 = (const float4*)(sW + (k4 * 4 + j) * NC);
#pragma unroll
            for (int q = 0; q < 4; ++q) ((float4*)wv)[q] = wr4[q];
            float xj = xs[j];
#pragma unroll
            for (int c = 0; c < 16; ++c) acc[c] = fmaf(xj, wv[c], acc[c]);
        }
    }
    if (!rv) return;
    float bm[16];
#pragma unroll
    for (int q = 0; q < 4; ++q) ((float4*)bm)[q] = ((const float4*)bm2)[q];
    float l[16];
#pragma unroll
    for (int c = 0; c < 16; ++c) l[c] = acc[c] + bm[c];
    float m = l[0];
#pragma unroll
    for (int c = 1; c < 16; ++c) m = fmaxf(m, l[c]);
    float ssum = 0.0f;
#pragma unroll
    for (int c = 0; c < 16; ++c) {
        l[c] = expf(l[c] - m);
        ssum += l[c];
    }
    float inv = 1.0f / ssum;
    float4* op = (float4*)(out + (size_t)rowc * NC);
#pragma unroll
    for (int q = 0; q < 4; ++q)
        op[q] = make_float4(l[q * 4] * inv, l[q * 4 + 1] * inv,
                            l[q * 4 + 2] * inv, l[q * 4 + 3] * inv);
}

extern "C" void kernel_launch(void* const* d_in, const int* in_sizes, int n_in,
                              void* d_out, int out_size, void* d_ws, size_t ws_size,
                              hipStream_t stream) {
    const float* x   = (const float*)d_in[0];
    const int*   ei  = (const int*)d_in[1];   // (2, E): [0,E)=src, [E,2E)=dst
    const float* ew  = (const float*)d_in[2];
    const float* W1  = (const float*)d_in[3];
    const float* b1  = (const float*)d_in[4];
    const float* W2  = (const float*)d_in[5];
    const float* b2  = (const float*)d_in[6];
    const float* Wm1 = (const float*)d_in[7];
    const float* bm1 = (const float*)d_in[8];
    const float* Wm2 = (const float*)d_in[9];
    const float* bm2 = (const float*)d_in[10];
    float* out = (float*)d_out;

    char* base = (char*)d_ws;
    float* dinv   = (float*)base;
    float* A      = (float*)(base + 400128);
    float* B      = (float*)(base + 26000128);
    int*   rowptr = (int*)(base + 51600128);        // (NN+1) ints
    int2*  pairsS = (int2*)(base + 52000256);       // FULL only
    // temporaries aliasing A / B before they're live:
    int2*  tmp    = (int2*)(base + 400128);         // in A, dead after k_sort
    int*   counts = (int*)(base + 26000128);        // in B, dead after k_sort
    int*   bsum   = (int*)(base + 26000128 + 306544);
    int*   bpref  = (int*)(base + 26000128 + 306944);

    const int* src = ei;
    const int* dst = ei + NE;

    const bool full  = ws_size >= (size_t)64800912;
    const bool douta = !full && ws_size >= (size_t)52000912;
    const int g_node = (NN + 255) / 256;   // 391
    const int g_g1   = (NN + 63) / 64;     // 1563
    const int g_g64  = (NN + 63) / 64;     // 1563
    const int g_agg  = (NN + 3) / 4;       // 25000
    const int g_red  = (NN * (HD / 4) + 255) / 256;  // 6250
    const int g_out  = (NN + 255) / 256;   // 391
    int* eid = (int*)d_out;

    if (full || douta) {
        // bucket build (LDS int atomics only)
        k_count<<<dim3(NBLK), dim3(256), 0, stream>>>(dst, counts);
        k_scan1<<<dim3(SCB), dim3(256), 0, stream>>>(counts, bsum);
        k_scan2<<<dim3(1), dim3(128), 0, stream>>>(bsum, bpref);
        k_scan3<<<dim3((CM + 255) / 256), dim3(256), 0, stream>>>(counts, bpref);
        if (full) {
            k_fill2<true><<<dim3(NBLK), dim3(256), 0, stream>>>(src, dst, ew, counts, tmp);
            k_sort<true><<<dim3(NT), dim3(256), 0, stream>>>(counts, tmp, pairsS, nullptr, rowptr, ew, dinv);
        } else {
            k_fill2<false><<<dim3(NBLK), dim3(256), 0, stream>>>(src, dst, ew, counts, tmp);
            k_sort<false><<<dim3(NT), dim3(256), 0, stream>>>(counts, tmp, nullptr, eid, rowptr, ew, dinv);
        }
        // layer 1: g1 = dinv .* (x @ W1)  (tmp dead -> A writable)
        k_gemm1<true><<<dim3(g_g1), dim3(256), 0, stream>>>(x, W1, dinv, A);
        if (full)
            k_agg<true><<<dim3(g_agg), dim3(256), 0, stream>>>(rowptr, pairsS, nullptr, src, ew, dinv, A, B);
        else
            k_agg<false><<<dim3(g_agg), dim3(256), 0, stream>>>(rowptr, nullptr, eid, src, ew, dinv, A, B);
        // layer 2: g2 = dinv .* (relu(agg1+b1) @ W2)
        k_gemm64<false, true><<<dim3(g_g64), dim3(256), 0, stream>>>(B, b1, W2, nullptr, dinv, A);
        if (full)
            k_agg<true><<<dim3(g_agg), dim3(256), 0, stream>>>(rowptr, pairsS, nullptr, src, ew, dinv, A, B);
        else
            k_agg<false><<<dim3(g_agg), dim3(256), 0, stream>>>(rowptr, nullptr, eid, src, ew, dinv, A, B);
        // MLP head + softmax (no scaling)
        k_gemm64<true, false><<<dim3(g_g64), dim3(256), 0, stream>>>(B, b2, Wm1, bm1, dinv, A);
        k_out<<<dim3(g_out), dim3(256), 0, stream>>>(A, Wm2, bm2, out);
    } else {
        // fallback: atomic scatter (h-space, unscaled producers)
        k_init_fb<<<dim3(g_node), dim3(256), 0, stream>>>(dinv);
        k_edge_fb<<<dim3(NE / 256), dim3(256), 0, stream>>>(dst, ew, dinv);
        k_dinv_fb<<<dim3(g_node), dim3(256), 0, stream>>>(dinv);
        k_gemm1<false><<<dim3(g_g1), dim3(256), 0, stream>>>(x, W1, dinv, A);
        k_selfloop<<<dim3(g_red), dim3(256), 0, stream>>>(A, dinv, B);
        k_scatter<<<dim3(NE / 4), dim3(256), 0, stream>>>(src, dst, ew, dinv, A, B);
        k_gemm64<false, false><<<dim3(g_g64), dim3(256), 0, stream>>>(B, b1, W2, nullptr, dinv, A);
        k_selfloop<<<dim3(g_red), dim3(256), 0, stream>>>(A, dinv, B);
        k_scatter<<<dim3(NE / 4), dim3(256), 0, stream>>>(src, dst, ew, dinv, A, B);
        k_gemm64<true, false><<<dim3(g_g64), dim3(256), 0, stream>>>(B, b2, Wm1, bm1, dinv, A);
        k_out<<<dim3(g_out), dim3(256), 0, stream>>>(A, Wm2, bm2, out);
    }
}

// Round 17
// 457.662 us; speedup vs baseline: 1.0715x; 1.0474x over previous
//
#include <hip/hip_runtime.h>
#include <cstdint>
#include <cstddef>

// Problem constants (match reference)
#define NN 100000   // nodes
#define NE 1600000  // edges
#define IN_F 256    // input feats
#define HD 64       // hidden width
#define NC 16       // classes

// Bucketed-build constants
#define NT 391      // dst tiles of 256 nodes: tile = dst >> 8
#define NBLK 196    // count/fill blocks
#define EPB 8192    // edges per count/fill block (NBLK*EPB >= NE)
#define CM (NT * NBLK)   // counts elems = 76,636
#define SCB 75      // scan blocks: ceil(CM/1024)

// ---------------------------------------------------------------------------
// Workspace layout (bytes) — guaranteed budget 52,000,912 (proven R4-R7):
//   dinv   @ 0             NN floats                              400,000
//   A      @ 400,128       NN*64 floats (g1 -> g2 -> h3)       25,600,000
//          (tmp int2[NE] = 12.8 MB aliases A BEFORE k_gemm1 runs)
//   B      @ 26,000,128    NN*64 floats (agg1 -> agg2)         25,600,000
//          (counts/bsum/bpref alias B's head, dead after k_sort)
//   rowptr @ 51,600,128    (NN+1) ints                             400,004
//   [FULL only] pairsS @ 52,000,256  NE int2 (src|dl<<17, ew)  12,800,000
// Configs (by ws_size, constant per run -> graph-safe):
//   FULL (ws >= 64,800,912): row-sorted (src,ew) pairs in ws; 1-indirection.
//   DOUT (ws >= 52,000,912): row-sorted edge-ids in d_out; 2-indirection.
//   FALLBACK (else): atomic-scatter path.
//
// R15 changes (resubmitted x3 — broker timeouts, never measured):
//   R14 measured 479.3 µs. k_agg landed 64.5 µs x2 (win, leave it).
//   k_gemm1 = 64.4 µs at VALU 41% / HBM 1.2 TB/s / 0 conflicts —
//   LDS-read-bound: 4x4 tile is 2 B/FMA = 3.2 GB = 47 µs LDS floor. Fixes:
//   (1) k_gemm1: 128-thread blocks, 4 rows x 8 cols/thread -> 1.5 B/FMA
//       (2.4 GB -> 35 µs floor), same 64-row/32-k staged structure,
//       grid 1563 (6 blocks x 2 waves = 12 waves/CU).
//   (2) k_gemm64: LDS-staged both operands (sIn[64][68] k-major + sW,
//       33.8 KB, 4 blocks/CU) with input bias+relu fused into staging —
//       removes the R10-style broadcast-load wall (~1 TB/s cap).
//   k-order per output unchanged in both -> numerics identical.
// No global atomics and no LDS *float* atomics anywhere on the main path.
// ---------------------------------------------------------------------------

// ---------------- tile-bucket build (LDS int atomics only) -----------------

__global__ __launch_bounds__(256) void k_count(const int* __restrict__ dstA,
                                               int* __restrict__ counts) {
    __shared__ int hist[NT];
    int tid = threadIdx.x;
    for (int t = tid; t < NT; t += 256) hist[t] = 0;
    __syncthreads();
    int base = blockIdx.x * EPB;
#pragma unroll
    for (int i = 0; i < 32; ++i) {
        int e = base + i * 256 + tid;
        if (e < NE) atomicAdd(&hist[dstA[e] >> 8], 1);  // native ds_add_u32
    }
    __syncthreads();
    for (int t = tid; t < NT; t += 256)
        counts[t * NBLK + blockIdx.x] = hist[t];
}

// exclusive scan of counts[CM] in place
__global__ __launch_bounds__(256) void k_scan1(int* __restrict__ c,
                                               int* __restrict__ bsum) {
    __shared__ int ss[256];
    int t = threadIdx.x;
    int base = blockIdx.x * 1024 + t * 4;
    int c0 = (base + 0 < CM) ? c[base + 0] : 0;
    int c1 = (base + 1 < CM) ? c[base + 1] : 0;
    int c2 = (base + 2 < CM) ? c[base + 2] : 0;
    int c3 = (base + 3 < CM) ? c[base + 3] : 0;
    int tsum = c0 + c1 + c2 + c3;
    ss[t] = tsum;
    __syncthreads();
    for (int off = 1; off < 256; off <<= 1) {
        int v = (t >= off) ? ss[t - off] : 0;
        __syncthreads();
        ss[t] += v;
        __syncthreads();
    }
    int excl = ss[t] - tsum;
    if (t == 255) bsum[blockIdx.x] = ss[255];
    if (base + 0 < CM) c[base + 0] = excl;
    if (base + 1 < CM) c[base + 1] = excl + c0;
    if (base + 2 < CM) c[base + 2] = excl + c0 + c1;
    if (base + 3 < CM) c[base + 3] = excl + c0 + c1 + c2;
}

__global__ __launch_bounds__(128) void k_scan2(const int* __restrict__ bsum,
                                               int* __restrict__ bpref) {
    __shared__ int ss[128];
    int t = threadIdx.x;
    int v = (t < SCB) ? bsum[t] : 0;
    ss[t] = v;
    __syncthreads();
    for (int off = 1; off < 128; off <<= 1) {
        int u = (t >= off) ? ss[t - off] : 0;
        __syncthreads();
        ss[t] += u;
        __syncthreads();
    }
    if (t < SCB) bpref[t] = ss[t] - v;
}

__global__ __launch_bounds__(256) void k_scan3(int* __restrict__ c,
                                               const int* __restrict__ bpref) {
    int i = blockIdx.x * 256 + threadIdx.x;
    if (i < CM) c[i] += bpref[i >> 10];
}

// fill tile buckets: tmp[pos] = FULL ? (src|dl<<17, ew) : (eid, dl)
template <bool FULL>
__global__ __launch_bounds__(256) void k_fill2(const int* __restrict__ srcA,
                                               const int* __restrict__ dstA,
                                               const float* __restrict__ ew,
                                               const int* __restrict__ counts,
                                               int2* __restrict__ tmp) {
    __shared__ int basel[NT];
    int tid = threadIdx.x;
    for (int t = tid; t < NT; t += 256) basel[t] = counts[t * NBLK + blockIdx.x];
    __syncthreads();
    int eb = blockIdx.x * EPB;
#pragma unroll
    for (int i = 0; i < 32; ++i) {
        int e = eb + i * 256 + tid;
        if (e < NE) {
            int d = dstA[e];
            int pos = atomicAdd(&basel[d >> 8], 1);  // native LDS int atomic
            if (FULL)
                tmp[pos] = make_int2(srcA[e] | ((d & 255) << 17),
                                     __float_as_int(ew[e]));
            else
                tmp[pos] = make_int2(e, d & 255);
        }
    }
}

// per-tile counting sort to row granularity. Writes rowptr + sorted payload.
// Fused degree/dinv tail — after the scatter, each thread sums its own
// row's edge weights (payload is L2-hot) and writes dinv[row] = rsqrt(1+sum).
template <bool FULL>
__global__ __launch_bounds__(256) void k_sort(const int* __restrict__ counts,
                                              const int2* __restrict__ tmp,
                                              int2* __restrict__ outP,
                                              int* __restrict__ outE,
                                              int* __restrict__ rowptr,
                                              const float* __restrict__ ew,
                                              float* __restrict__ dinv) {
    __shared__ int hist[256], ss[256], bases[256];
    int tid = threadIdx.x;
    int tile = blockIdx.x;
    int bs = counts[tile * NBLK];
    int be = (tile + 1 < NT) ? counts[(tile + 1) * NBLK] : NE;
    hist[tid] = 0;
    __syncthreads();
    for (int p = bs + tid; p < be; p += 256) {
        int dl = FULL ? ((tmp[p].x >> 17) & 255) : tmp[p].y;
        atomicAdd(&hist[dl], 1);  // native LDS int atomic
    }
    __syncthreads();
    int v = hist[tid];
    ss[tid] = v;
    __syncthreads();
    for (int off = 1; off < 256; off <<= 1) {
        int u = (tid >= off) ? ss[tid - off] : 0;
        __syncthreads();
        ss[tid] += u;
        __syncthreads();
    }
    int excl = ss[tid] - v;
    bases[tid] = bs + excl;
    int row = tile * 256 + tid;
    if (row < NN) rowptr[row] = bs + excl;
    if (tile == NT - 1 && tid == 0) rowptr[NN] = NE;
    __syncthreads();
    for (int p = bs + tid; p < be; p += 256) {
        int2 t2 = tmp[p];
        int dl = FULL ? ((t2.x >> 17) & 255) : t2.y;
        int pos = atomicAdd(&bases[dl], 1);
        if (FULL) outP[pos] = t2;
        else      outE[pos] = t2.x;
    }
    __syncthreads();  // global writes above visible to this block below
    if (row < NN) {
        int p0 = bs + excl, p1 = bs + excl + v;
        float s = 1.0f;  // self-loop weight
        for (int p = p0; p < p1; ++p)
            s += FULL ? __int_as_float(outP[p].y) : ew[outE[p]];
        dinv[row] = rsqrtf(s);
    }
}

// aggregate in g-space: g = dinv .* h (producers pre-scale rows).
// out[d] = dinv[d] * (g[d] + sum_e w_e * g[src_e])
//        = dinv[d]^2*h[d] + sum_e dinv[d]*w_e*dinv[s]*h[s]  (== reference)
// R14 (proven 64.5 µs): unclamped 8-wide main loop + 4-wide + scalar tail.
template <bool FULL>
__global__ __launch_bounds__(256) void k_agg(const int* __restrict__ rowptr,
                                             const int2* __restrict__ pairsS,
                                             const int* __restrict__ eid,
                                             const int* __restrict__ srcA,
                                             const float* __restrict__ ew,
                                             const float* __restrict__ dinv,
                                             const float* __restrict__ g,
                                             float* __restrict__ agg) {
    int row = blockIdx.x * 4 + (threadIdx.x >> 6);
    int lane = threadIdx.x & 63;
    if (row >= NN) return;
    int p = rowptr[row], pe = rowptr[row + 1];
    float di = dinv[row];
    float acc = g[(size_t)row * HD + lane];   // self term: g[d]
    // 8-wide main loop: full groups only — no clamp VALU, no dead loads.
    for (; p + 8 <= pe; p += 8) {
        int   sv[8];
        float wv[8];
        if (FULL) {
#pragma unroll
            for (int i = 0; i < 8; ++i) {
                int2 v = pairsS[p + i];
                sv[i] = v.x & 0x1FFFF;
                wv[i] = __int_as_float(v.y);
            }
        } else {
            int ev[8];
#pragma unroll
            for (int i = 0; i < 8; ++i) ev[i] = eid[p + i];
#pragma unroll
            for (int i = 0; i < 8; ++i) { sv[i] = srcA[ev[i]]; wv[i] = ew[ev[i]]; }
        }
        float gs[8];
#pragma unroll
        for (int i = 0; i < 8; ++i)
            gs[i] = g[(size_t)sv[i] * HD + lane];
#pragma unroll
        for (int i = 0; i < 8; ++i)
            acc = fmaf(wv[i], gs[i], acc);
    }
    // 4-wide (R12-proven)
    for (; p + 4 <= pe; p += 4) {
        if (FULL) {
            int2 v0 = pairsS[p], v1 = pairsS[p + 1],
                 v2 = pairsS[p + 2], v3 = pairsS[p + 3];
            int s0 = v0.x & 0x1FFFF, s1 = v1.x & 0x1FFFF,
                s2 = v2.x & 0x1FFFF, s3 = v3.x & 0x1FFFF;
            float g0 = g[(size_t)s0 * HD + lane];
            float g1 = g[(size_t)s1 * HD + lane];
            float g2 = g[(size_t)s2 * HD + lane];
            float g3 = g[(size_t)s3 * HD + lane];
            acc = fmaf(__int_as_float(v0.y), g0, acc);
            acc = fmaf(__int_as_float(v1.y), g1, acc);
            acc = fmaf(__int_as_float(v2.y), g2, acc);
            acc = fmaf(__int_as_float(v3.y), g3, acc);
        } else {
            int e0 = eid[p], e1 = eid[p + 1], e2 = eid[p + 2], e3 = eid[p + 3];
            int s0 = srcA[e0], s1 = srcA[e1], s2 = srcA[e2], s3 = srcA[e3];
            float g0 = g[(size_t)s0 * HD + lane];
            float g1 = g[(size_t)s1 * HD + lane];
            float g2 = g[(size_t)s2 * HD + lane];
            float g3 = g[(size_t)s3 * HD + lane];
            acc = fmaf(ew[e0], g0, acc);
            acc = fmaf(ew[e1], g1, acc);
            acc = fmaf(ew[e2], g2, acc);
            acc = fmaf(ew[e3], g3, acc);
        }
    }
    // scalar tail
    for (; p < pe; ++p) {
        if (FULL) {
            int2 v = pairsS[p];
            acc = fmaf(__int_as_float(v.y),
                       g[(size_t)(v.x & 0x1FFFF) * HD + lane], acc);
        } else {
            int e = eid[p];
            acc = fmaf(ew[e], g[(size_t)srcA[e] * HD + lane], acc);
        }
    }
    agg[(size_t)row * HD + lane] = di * acc;
}

// ---------------------------------------------------------------------------
// GEMM1: x[N,256] @ W1[256,64]. 64 rows/block, 128 THREADS, thread tile
// 4 rows x 8 cols (rs=tid>>3, cg=tid&7) — 1.5 B LDS/FMA (R12's 4x4 was
// 2 B/FMA = 47 µs LDS-floor, measured 64.4). Grid 1563, 6 blocks x 2
// waves = 12 waves/CU. K chunked by 32, both operands LDS-staged.
// SCALE: multiply output row by dinv[row] (g-space).
// ---------------------------------------------------------------------------
template <bool SCALE>
__global__ __launch_bounds__(128, 3) void k_gemm1(const float* __restrict__ x,
                                                  const float* __restrict__ W1,
                                                  const float* __restrict__ dinv,
                                                  float* __restrict__ h0) {
    __shared__ float sX[32][68];     // [k][row], padded (8.7 KB)
    __shared__ float sW[32][64];     // [k][col] (8 KB)
    int tid = threadIdx.x;           // 0..127
    int rs  = tid >> 3;              // 0..15: row group (4 rows each)
    int cg  = tid & 7;               // 0..7 : col group (8 cols each)
    int base = blockIdx.x * 64;

    int f4   = tid >> 5;             // 0..3
    int srow = tid & 31;

    float acc[4][8];
#pragma unroll
    for (int r = 0; r < 4; ++r)
#pragma unroll
        for (int c = 0; c < 8; ++c) acc[r][c] = 0.0f;

    for (int kc = 0; kc < IN_F; kc += 32) {
        __syncthreads();
        // stage W chunk: rows kc..kc+31 of W1, contiguous 8 KB (512 f4)
        {
            const float4* wsrc = (const float4*)(W1 + (size_t)kc * HD);
            float4* wdst = (float4*)&sW[0][0];
#pragma unroll
            for (int q = 0; q < 4; ++q) wdst[q * 128 + tid] = wsrc[q * 128 + tid];
        }
        // stage x chunk k-major: sX[k][row] = x[base+row][kc+k]
#pragma unroll
        for (int q = 0; q < 2; ++q) {
            int grow = q * 32 + srow;
            int growc = (base + grow < NN) ? (base + grow) : (NN - 1);
#pragma unroll
            for (int q2 = 0; q2 < 2; ++q2) {
                int koff = q2 * 16 + f4 * 4;
                float4 v = *(const float4*)(x + (size_t)growc * IN_F + kc + koff);
                sX[koff + 0][grow] = v.x;
                sX[koff + 1][grow] = v.y;
                sX[koff + 2][grow] = v.z;
                sX[koff + 3][grow] = v.w;
            }
        }
        __syncthreads();
        // compute: per k: 1 b128 x + 2 b128 W + 32 FMA
#pragma unroll 4
        for (int k = 0; k < 32; ++k) {
            float xs[4];
            *(float4*)xs = *(const float4*)&sX[k][rs * 4];
            float wv[8];
            *(float4*)(wv + 0) = *(const float4*)&sW[k][cg * 8];
            *(float4*)(wv + 4) = *(const float4*)&sW[k][cg * 8 + 4];
#pragma unroll
            for (int r = 0; r < 4; ++r) {
                float xj = xs[r];
#pragma unroll
                for (int c = 0; c < 8; ++c) acc[r][c] = fmaf(xj, wv[c], acc[r][c]);
            }
        }
    }
#pragma unroll
    for (int r = 0; r < 4; ++r) {
        int row = base + rs * 4 + r;
        if (row >= NN) continue;
        float di = SCALE ? dinv[row] : 1.0f;
        float* hp = h0 + (size_t)row * HD + cg * 8;
        *(float4*)(hp + 0) = make_float4(acc[r][0] * di, acc[r][1] * di,
                                         acc[r][2] * di, acc[r][3] * di);
        *(float4*)(hp + 4) = make_float4(acc[r][4] * di, acc[r][5] * di,
                                         acc[r][6] * di, acc[r][7] * di);
    }
}

// ---------------------------------------------------------------------------
// 64x64 GEMM, LDS-staged both operands (the old version's broadcast reads
// of `in` hit the ~1 TB/s 16-lanes/address wall). Input bias+relu is fused
// into the staging write: sIn[k][row] = relu(in[row][k] + bin[k]) — both
// call sites apply it, identical arithmetic, k-order unchanged.
// 64 rows/block, 256 threads, 4x4 tile. LDS 33.8 KB -> 4 blocks/CU.
// BIASRELU: output += bout, relu. SCALEOUT: output row *= dinv[row].
// ---------------------------------------------------------------------------
template <bool BIASRELU, bool SCALEOUT>
__global__ __launch_bounds__(256, 4) void k_gemm64(const float* __restrict__ in,
                                                   const float* __restrict__ bin,
                                                   const float* __restrict__ W,
                                                   const float* __restrict__ bout,
                                                   const float* __restrict__ dinv,
                                                   float* __restrict__ outA) {
    __shared__ float sIn[64][68];    // relu(in+bin), k-major (17.4 KB)
    __shared__ float sW[64][64];     // (16 KB)
    int tid = threadIdx.x;
    int rs  = tid >> 4;              // 0..15: row group (4 rows each)
    int cg  = tid & 15;              // 0..15: col group (4 cols each)
    int base = blockIdx.x * 64;
    int f4   = tid >> 5;             // 0..7
    int srow = tid & 31;

    // stage W: 64x64 = 1024 f4
    {
        const float4* wsrc = (const float4*)W;
        float4* wdst = (float4*)&sW[0][0];
#pragma unroll
        for (int q = 0; q < 4; ++q) wdst[q * 256 + tid] = wsrc[q * 256 + tid];
    }
    // stage in with fused bias+relu, k-major
#pragma unroll
    for (int q2 = 0; q2 < 2; ++q2) {
        int koff = q2 * 32 + f4 * 4;
        float4 bb = *(const float4*)(bin + koff);
#pragma unroll
        for (int q = 0; q < 2; ++q) {
            int grow = q * 32 + srow;
            int growc = (base + grow < NN) ? (base + grow) : (NN - 1);
            float4 v = *(const float4*)(in + (size_t)growc * HD + koff);
            sIn[koff + 0][grow] = fmaxf(v.x + bb.x, 0.0f);
            sIn[koff + 1][grow] = fmaxf(v.y + bb.y, 0.0f);
            sIn[koff + 2][grow] = fmaxf(v.z + bb.z, 0.0f);
            sIn[koff + 3][grow] = fmaxf(v.w + bb.w, 0.0f);
        }
    }
    __syncthreads();

    float acc[4][4];
#pragma unroll
    for (int r = 0; r < 4; ++r)
#pragma unroll
        for (int c = 0; c < 4; ++c) acc[r][c] = 0.0f;

#pragma unroll 4
    for (int k = 0; k < HD; ++k) {
        float xs[4];
        *(float4*)xs = *(const float4*)&sIn[k][rs * 4];
        float wv[4];
        *(float4*)wv = *(const float4*)&sW[k][cg * 4];
#pragma unroll
        for (int r = 0; r < 4; ++r) {
            float hv = xs[r];
#pragma unroll
            for (int c = 0; c < 4; ++c) acc[r][c] = fmaf(hv, wv[c], acc[r][c]);
        }
    }

#pragma unroll
    for (int r = 0; r < 4; ++r) {
        int row = base + rs * 4 + r;
        if (row >= NN) continue;
        float* ha = outA + (size_t)row * HD + cg * 4;
        if (BIASRELU) {
            float bo[4];
            *(float4*)bo = *(const float4*)(bout + cg * 4);
            *(float4*)ha = make_float4(fmaxf(acc[r][0] + bo[0], 0.0f),
                                       fmaxf(acc[r][1] + bo[1], 0.0f),
                                       fmaxf(acc[r][2] + bo[2], 0.0f),
                                       fmaxf(acc[r][3] + bo[3], 0.0f));
        } else {
            float di = SCALEOUT ? dinv[row] : 1.0f;
            *(float4*)ha = make_float4(acc[r][0] * di, acc[r][1] * di,
                                       acc[r][2] * di, acc[r][3] * di);
        }
    }
}

// --- fallback path kernels ---
__global__ __launch_bounds__(256) void k_init_fb(float* __restrict__ deg) {
    int i = blockIdx.x * 256 + threadIdx.x;
    if (i < NN) deg[i] = 1.0f;
}
__global__ __launch_bounds__(256) void k_edge_fb(const int* __restrict__ dst,
                                                 const float* __restrict__ ew,
                                                 float* __restrict__ deg) {
    int e = blockIdx.x * 256 + threadIdx.x;
    if (e < NE) atomicAdd(&deg[dst[e]], ew[e]);
}
__global__ __launch_bounds__(256) void k_dinv_fb(float* __restrict__ deg) {
    int i = blockIdx.x * 256 + threadIdx.x;
    if (i < NN) {
        float d = deg[i];
        deg[i] = d > 0.0f ? rsqrtf(d) : 0.0f;
    }
}
// fallback producers are h-space and gemm64 fuses input bias+relu; the
// fallback path feeds raw h into gemm64 with bin — same semantics as before.
__global__ __launch_bounds__(256) void k_selfloop(const float* __restrict__ h,
                                                  const float* __restrict__ dinv,
                                                  float* __restrict__ agg) {
    int i = blockIdx.x * 256 + threadIdx.x;
    if (i >= NN * (HD / 4)) return;
    int row = i / (HD / 4);
    float di = dinv[row];
    float d2 = di * di;
    float4 v = ((const float4*)h)[i];
    ((float4*)agg)[i] = make_float4(v.x * d2, v.y * d2, v.z * d2, v.w * d2);
}
__global__ __launch_bounds__(256) void k_scatter(const int* __restrict__ src,
                                                 const int* __restrict__ dst,
                                                 const float* __restrict__ ew,
                                                 const float* __restrict__ dinv,
                                                 const float* __restrict__ h,
                                                 float* __restrict__ agg) {
    int e = blockIdx.x * 4 + (threadIdx.x >> 6);
    int lane = threadIdx.x & 63;
    if (e >= NE) return;
    int s = src[e];
    int d = dst[e];
    float nrm = dinv[s] * ew[e] * dinv[d];
    float v = h[(size_t)s * HD + lane] * nrm;
    atomicAdd(&agg[(size_t)d * HD + lane], v);
}

// logits = h3 @ Wm2 + bm2, softmax. Wm2 (4 KB) in LDS, 1 row/thread (grid 391).
__global__ __launch_bounds__(256, 4) void k_out(const float* __restrict__ h3,
                                                const float* __restrict__ Wm2,
                                                const float* __restrict__ bm2,
                                                float* __restrict__ out) {
    __shared__ float sW[HD * NC];
    int tid = threadIdx.x;
    ((float4*)sW)[tid] = ((const float4*)Wm2)[tid];
    __syncthreads();
    int row = blockIdx.x * 256 + tid;
    bool rv = row < NN;
    int rowc = rv ? row : (NN - 1);
    float acc[16];
#pragma unroll
    for (int c = 0; c < 16; ++c) acc[c] = 0.0f;

    for (int k4 = 0; k4 < 16; ++k4) {
        float xs[4];
        *(float4*)xs = *(const float4*)(h3 + (size_t)rowc * HD + k4 * 4);
#pragma unroll
        for (int j = 0; j < 4; ++j) {
            float wv[16];
            const float4* wr4 = (const float4*)(sW + (k4 * 4 + j) * NC);
#pragma unroll
            for (int q = 0; q < 4; ++q) ((float4*)wv)[q] = wr4[q];
            float xj = xs[j];
#pragma unroll
            for (int c = 0; c < 16; ++c) acc[c] = fmaf(xj, wv[c], acc[c]);
        }
    }
    if (!rv) return;
    float bm[16];
#pragma unroll
    for (int q = 0; q < 4; ++q) ((float4*)bm)[q] = ((const float4*)bm2)[q];
    float l[16];
#pragma unroll
    for (int c = 0; c < 16; ++c) l[c] = acc[c] + bm[c];
    float m = l[0];
#pragma unroll
    for (int c = 1; c < 16; ++c) m = fmaxf(m, l[c]);
    float ssum = 0.0f;
#pragma unroll
    for (int c = 0; c < 16; ++c) {
        l[c] = expf(l[c] - m);
        ssum += l[c];
    }
    float inv = 1.0f / ssum;
    float4* op = (float4*)(out + (size_t)rowc * NC);
#pragma unroll
    for (int q = 0; q < 4; ++q)
        op[q] = make_float4(l[q * 4] * inv, l[q * 4 + 1] * inv,
                            l[q * 4 + 2] * inv, l[q * 4 + 3] * inv);
}

extern "C" void kernel_launch(void* const* d_in, const int* in_sizes, int n_in,
                              void* d_out, int out_size, void* d_ws, size_t ws_size,
                              hipStream_t stream) {
    const float* x   = (const float*)d_in[0];
    const int*   ei  = (const int*)d_in[1];   // (2, E): [0,E)=src, [E,2E)=dst
    const float* ew  = (const float*)d_in[2];
    const float* W1  = (const float*)d_in[3];
    const float* b1  = (const float*)d_in[4];
    const float* W2  = (const float*)d_in[5];
    const float* b2  = (const float*)d_in[6];
    const float* Wm1 = (const float*)d_in[7];
    const float* bm1 = (const float*)d_in[8];
    const float* Wm2 = (const float*)d_in[9];
    const float* bm2 = (const float*)d_in[10];
    float* out = (float*)d_out;

    char* base = (char*)d_ws;
    float* dinv   = (float*)base;
    float* A      = (float*)(base + 400128);
    float* B      = (float*)(base + 26000128);
    int*   rowptr = (int*)(base + 51600128);        // (NN+1) ints
    int2*  pairsS = (int2*)(base + 52000256);       // FULL only
    // temporaries aliasing A / B before they're live:
    int2*  tmp    = (int2*)(base + 400128);         // in A, dead after k_sort
    int*   counts = (int*)(base + 26000128);        // in B, dead after k_sort
    int*   bsum   = (int*)(base + 26000128 + 306544);
    int*   bpref  = (int*)(base + 26000128 + 306944);

    const int* src = ei;
    const int* dst = ei + NE;

    const bool full  = ws_size >= (size_t)64800912;
    const bool douta = !full && ws_size >= (size_t)52000912;
    const int g_node = (NN + 255) / 256;   // 391
    const int g_g1   = (NN + 63) / 64;     // 1563 (128-thread blocks)
    const int g_g64  = (NN + 63) / 64;     // 1563
    const int g_agg  = (NN + 3) / 4;       // 25000
    const int g_red  = (NN * (HD / 4) + 255) / 256;  // 6250
    const int g_out  = (NN + 255) / 256;   // 391
    int* eid = (int*)d_out;

    if (full || douta) {
        // bucket build (LDS int atomics only)
        k_count<<<dim3(NBLK), dim3(256), 0, stream>>>(dst, counts);
        k_scan1<<<dim3(SCB), dim3(256), 0, stream>>>(counts, bsum);
        k_scan2<<<dim3(1), dim3(128), 0, stream>>>(bsum, bpref);
        k_scan3<<<dim3((CM + 255) / 256), dim3(256), 0, stream>>>(counts, bpref);
        if (full) {
            k_fill2<true><<<dim3(NBLK), dim3(256), 0, stream>>>(src, dst, ew, counts, tmp);
            k_sort<true><<<dim3(NT), dim3(256), 0, stream>>>(counts, tmp, pairsS, nullptr, rowptr, ew, dinv);
        } else {
            k_fill2<false><<<dim3(NBLK), dim3(256), 0, stream>>>(src, dst, ew, counts, tmp);
            k_sort<false><<<dim3(NT), dim3(256), 0, stream>>>(counts, tmp, nullptr, eid, rowptr, ew, dinv);
        }
        // layer 1: g1 = dinv .* (x @ W1)  (tmp dead -> A writable)
        k_gemm1<true><<<dim3(g_g1), dim3(128), 0, stream>>>(x, W1, dinv, A);
        if (full)
            k_agg<true><<<dim3(g_agg), dim3(256), 0, stream>>>(rowptr, pairsS, nullptr, src, ew, dinv, A, B);
        else
            k_agg<false><<<dim3(g_agg), dim3(256), 0, stream>>>(rowptr, nullptr, eid, src, ew, dinv, A, B);
        // layer 2: g2 = dinv .* (relu(agg1+b1) @ W2)
        k_gemm64<false, true><<<dim3(g_g64), dim3(256), 0, stream>>>(B, b1, W2, nullptr, dinv, A);
        if (full)
            k_agg<true><<<dim3(g_agg), dim3(256), 0, stream>>>(rowptr, pairsS, nullptr, src, ew, dinv, A, B);
        else
            k_agg<false><<<dim3(g_agg), dim3(256), 0, stream>>>(rowptr, nullptr, eid, src, ew, dinv, A, B);
        // MLP head + softmax (no scaling)
        k_gemm64<true, false><<<dim3(g_g64), dim3(256), 0, stream>>>(B, b2, Wm1, bm1, dinv, A);
        k_out<<<dim3(g_out), dim3(256), 0, stream>>>(A, Wm2, bm2, out);
    } else {
        // fallback: atomic scatter (h-space, unscaled producers)
        k_init_fb<<<dim3(g_node), dim3(256), 0, stream>>>(dinv);
        k_edge_fb<<<dim3(NE / 256), dim3(256), 0, stream>>>(dst, ew, dinv);
        k_dinv_fb<<<dim3(g_node), dim3(256), 0, stream>>>(dinv);
        k_gemm1<false><<<dim3(g_g1), dim3(128), 0, stream>>>(x, W1, dinv, A);
        k_selfloop<<<dim3(g_red), dim3(256), 0, stream>>>(A, dinv, B);
        k_scatter<<<dim3(NE / 4), dim3(256), 0, stream>>>(src, dst, ew, dinv, A, B);
        k_gemm64<false, false><<<dim3(g_g64), dim3(256), 0, stream>>>(B, b1, W2, nullptr, dinv, A);
        k_selfloop<<<dim3(g_red), dim3(256), 0, stream>>>(A, dinv, B);
        k_scatter<<<dim3(NE / 4), dim3(256), 0, stream>>>(src, dst, ew, dinv, A, B);
        k_gemm64<true, false><<<dim3(g_g64), dim3(256), 0, stream>>>(B, b2, Wm1, bm1, dinv, A);
        k_out<<<dim3(g_out), dim3(256), 0, stream>>>(A, Wm2, bm2, out);
    }
}

// Round 18
// 451.970 us; speedup vs baseline: 1.0850x; 1.0126x over previous
//
#include <hip/hip_runtime.h>
#include <cstdint>
#include <cstddef>

// Problem constants (match reference)
#define NN 100000   // nodes
#define NE 1600000  // edges
#define IN_F 256    // input feats
#define HD 64       // hidden width
#define NC 16       // classes

// Bucketed-build constants (R16: NBLK 196 -> 784 for 3.06 blocks/CU)
#define NT 391      // dst tiles of 256 nodes: tile = dst >> 8
#define NBLK 784    // count/fill blocks
#define EPB 2048    // edges per count/fill block (NBLK*EPB >= NE)
#define CM (NT * NBLK)   // counts elems = 306,544
#define SCB 300     // scan blocks: ceil(CM/1024)

// ---------------------------------------------------------------------------
// Workspace layout (bytes) — guaranteed budget 52,000,912:
//   dinv   @ 0             NN floats                              400,000
//   A      @ 400,128       NN*64 floats (g1 -> g2 -> h3)       25,600,000
//          (tmp int2[NE] = 12.8 MB aliases A BEFORE k_gemm1 runs)
//   B      @ 26,000,128    NN*64 floats (agg1 -> agg2)         25,600,000
//          (counts[CM]=1.23MB + bsum/bpref alias B's head, dead after k_sort)
//   rowptr @ 51,600,128    (NN+1) ints                             400,004
//   [FULL only] pairsS @ 52,000,256  NE int2 (src|dl<<17, ew)  12,800,000
//
// R16 changes (this round — R15 measured 457.7 µs):
//   (1) k_gemm1 = 65.0 µs unchanged vs R12 despite 2->1.5 B/FMA — model
//       revised: ds_read_b128 ISSUE throughput (~12 cyc, m134) binds.
//       R12: 3.2M wave-b128 = 62.5 µs (matches 64.4); R15: 2.4M = 47+slack.
//       Fix: 64-thread (1-wave) blocks, 8x8 thread tile = 16 FMA/b128
//       (1.6M wave-b128 -> ~25-31 µs DS, FMA floor 21 µs). Grid 1563 =
//       6.1 waves/CU; barriers ~free in 1-wave blocks; per-thread-row
//       staging loads give 64 lines/instr MLP. k-order unchanged.
//   (2) Build grid x4: NBLK 784 / EPB 2048 (count/fill were 196 blocks =
//       0.77/CU). scan2 widened to 512 threads (SCB=300); offsets updated.
// No global atomics and no LDS *float* atomics anywhere on the main path.
// ---------------------------------------------------------------------------

// ---------------- tile-bucket build (LDS int atomics only) -----------------

__global__ __launch_bounds__(256) void k_count(const int* __restrict__ dstA,
                                               int* __restrict__ counts) {
    __shared__ int hist[NT];
    int tid = threadIdx.x;
    for (int t = tid; t < NT; t += 256) hist[t] = 0;
    __syncthreads();
    int base = blockIdx.x * EPB;
#pragma unroll
    for (int i = 0; i < 8; ++i) {
        int e = base + i * 256 + tid;
        if (e < NE) atomicAdd(&hist[dstA[e] >> 8], 1);  // native ds_add_u32
    }
    __syncthreads();
    for (int t = tid; t < NT; t += 256)
        counts[t * NBLK + blockIdx.x] = hist[t];
}

// exclusive scan of counts[CM] in place
__global__ __launch_bounds__(256) void k_scan1(int* __restrict__ c,
                                               int* __restrict__ bsum) {
    __shared__ int ss[256];
    int t = threadIdx.x;
    int base = blockIdx.x * 1024 + t * 4;
    int c0 = (base + 0 < CM) ? c[base + 0] : 0;
    int c1 = (base + 1 < CM) ? c[base + 1] : 0;
    int c2 = (base + 2 < CM) ? c[base + 2] : 0;
    int c3 = (base + 3 < CM) ? c[base + 3] : 0;
    int tsum = c0 + c1 + c2 + c3;
    ss[t] = tsum;
    __syncthreads();
    for (int off = 1; off < 256; off <<= 1) {
        int v = (t >= off) ? ss[t - off] : 0;
        __syncthreads();
        ss[t] += v;
        __syncthreads();
    }
    int excl = ss[t] - tsum;
    if (t == 255) bsum[blockIdx.x] = ss[255];
    if (base + 0 < CM) c[base + 0] = excl;
    if (base + 1 < CM) c[base + 1] = excl + c0;
    if (base + 2 < CM) c[base + 2] = excl + c0 + c1;
    if (base + 3 < CM) c[base + 3] = excl + c0 + c1 + c2;
}

// scan of SCB block sums (SCB=300 <= 512)
__global__ __launch_bounds__(512) void k_scan2(const int* __restrict__ bsum,
                                               int* __restrict__ bpref) {
    __shared__ int ss[512];
    int t = threadIdx.x;
    int v = (t < SCB) ? bsum[t] : 0;
    ss[t] = v;
    __syncthreads();
    for (int off = 1; off < 512; off <<= 1) {
        int u = (t >= off) ? ss[t - off] : 0;
        __syncthreads();
        ss[t] += u;
        __syncthreads();
    }
    if (t < SCB) bpref[t] = ss[t] - v;
}

__global__ __launch_bounds__(256) void k_scan3(int* __restrict__ c,
                                               const int* __restrict__ bpref) {
    int i = blockIdx.x * 256 + threadIdx.x;
    if (i < CM) c[i] += bpref[i >> 10];
}

// fill tile buckets: tmp[pos] = FULL ? (src|dl<<17, ew) : (eid, dl)
template <bool FULL>
__global__ __launch_bounds__(256) void k_fill2(const int* __restrict__ srcA,
                                               const int* __restrict__ dstA,
                                               const float* __restrict__ ew,
                                               const int* __restrict__ counts,
                                               int2* __restrict__ tmp) {
    __shared__ int basel[NT];
    int tid = threadIdx.x;
    for (int t = tid; t < NT; t += 256) basel[t] = counts[t * NBLK + blockIdx.x];
    __syncthreads();
    int eb = blockIdx.x * EPB;
#pragma unroll
    for (int i = 0; i < 8; ++i) {
        int e = eb + i * 256 + tid;
        if (e < NE) {
            int d = dstA[e];
            int pos = atomicAdd(&basel[d >> 8], 1);  // native LDS int atomic
            if (FULL)
                tmp[pos] = make_int2(srcA[e] | ((d & 255) << 17),
                                     __float_as_int(ew[e]));
            else
                tmp[pos] = make_int2(e, d & 255);
        }
    }
}

// per-tile counting sort to row granularity. Writes rowptr + sorted payload.
// Fused degree/dinv tail — after the scatter, each thread sums its own
// row's edge weights (payload is L2-hot) and writes dinv[row] = rsqrt(1+sum).
template <bool FULL>
__global__ __launch_bounds__(256) void k_sort(const int* __restrict__ counts,
                                              const int2* __restrict__ tmp,
                                              int2* __restrict__ outP,
                                              int* __restrict__ outE,
                                              int* __restrict__ rowptr,
                                              const float* __restrict__ ew,
                                              float* __restrict__ dinv) {
    __shared__ int hist[256], ss[256], bases[256];
    int tid = threadIdx.x;
    int tile = blockIdx.x;
    int bs = counts[tile * NBLK];
    int be = (tile + 1 < NT) ? counts[(tile + 1) * NBLK] : NE;
    hist[tid] = 0;
    __syncthreads();
    for (int p = bs + tid; p < be; p += 256) {
        int dl = FULL ? ((tmp[p].x >> 17) & 255) : tmp[p].y;
        atomicAdd(&hist[dl], 1);  // native LDS int atomic
    }
    __syncthreads();
    int v = hist[tid];
    ss[tid] = v;
    __syncthreads();
    for (int off = 1; off < 256; off <<= 1) {
        int u = (tid >= off) ? ss[tid - off] : 0;
        __syncthreads();
        ss[tid] += u;
        __syncthreads();
    }
    int excl = ss[tid] - v;
    bases[tid] = bs + excl;
    int row = tile * 256 + tid;
    if (row < NN) rowptr[row] = bs + excl;
    if (tile == NT - 1 && tid == 0) rowptr[NN] = NE;
    __syncthreads();
    for (int p = bs + tid; p < be; p += 256) {
        int2 t2 = tmp[p];
        int dl = FULL ? ((t2.x >> 17) & 255) : t2.y;
        int pos = atomicAdd(&bases[dl], 1);
        if (FULL) outP[pos] = t2;
        else      outE[pos] = t2.x;
    }
    __syncthreads();  // global writes above visible to this block below
    if (row < NN) {
        int p0 = bs + excl, p1 = bs + excl + v;
        float s = 1.0f;  // self-loop weight
        for (int p = p0; p < p1; ++p)
            s += FULL ? __int_as_float(outP[p].y) : ew[outE[p]];
        dinv[row] = rsqrtf(s);
    }
}

// aggregate in g-space: g = dinv .* h (producers pre-scale rows).
// out[d] = dinv[d] * (g[d] + sum_e w_e * g[src_e])  (== reference)
// R14 (proven 64.5 µs): unclamped 8-wide main loop + 4-wide + scalar tail.
template <bool FULL>
__global__ __launch_bounds__(256) void k_agg(const int* __restrict__ rowptr,
                                             const int2* __restrict__ pairsS,
                                             const int* __restrict__ eid,
                                             const int* __restrict__ srcA,
                                             const float* __restrict__ ew,
                                             const float* __restrict__ dinv,
                                             const float* __restrict__ g,
                                             float* __restrict__ agg) {
    int row = blockIdx.x * 4 + (threadIdx.x >> 6);
    int lane = threadIdx.x & 63;
    if (row >= NN) return;
    int p = rowptr[row], pe = rowptr[row + 1];
    float di = dinv[row];
    float acc = g[(size_t)row * HD + lane];   // self term: g[d]
    // 8-wide main loop: full groups only — no clamp VALU, no dead loads.
    for (; p + 8 <= pe; p += 8) {
        int   sv[8];
        float wv[8];
        if (FULL) {
#pragma unroll
            for (int i = 0; i < 8; ++i) {
                int2 v = pairsS[p + i];
                sv[i] = v.x & 0x1FFFF;
                wv[i] = __int_as_float(v.y);
            }
        } else {
            int ev[8];
#pragma unroll
            for (int i = 0; i < 8; ++i) ev[i] = eid[p + i];
#pragma unroll
            for (int i = 0; i < 8; ++i) { sv[i] = srcA[ev[i]]; wv[i] = ew[ev[i]]; }
        }
        float gs[8];
#pragma unroll
        for (int i = 0; i < 8; ++i)
            gs[i] = g[(size_t)sv[i] * HD + lane];
#pragma unroll
        for (int i = 0; i < 8; ++i)
            acc = fmaf(wv[i], gs[i], acc);
    }
    // 4-wide (R12-proven)
    for (; p + 4 <= pe; p += 4) {
        if (FULL) {
            int2 v0 = pairsS[p], v1 = pairsS[p + 1],
                 v2 = pairsS[p + 2], v3 = pairsS[p + 3];
            int s0 = v0.x & 0x1FFFF, s1 = v1.x & 0x1FFFF,
                s2 = v2.x & 0x1FFFF, s3 = v3.x & 0x1FFFF;
            float g0 = g[(size_t)s0 * HD + lane];
            float g1 = g[(size_t)s1 * HD + lane];
            float g2 = g[(size_t)s2 * HD + lane];
            float g3 = g[(size_t)s3 * HD + lane];
            acc = fmaf(__int_as_float(v0.y), g0, acc);
            acc = fmaf(__int_as_float(v1.y), g1, acc);
            acc = fmaf(__int_as_float(v2.y), g2, acc);
            acc = fmaf(__int_as_float(v3.y), g3, acc);
        } else {
            int e0 = eid[p], e1 = eid[p + 1], e2 = eid[p + 2], e3 = eid[p + 3];
            int s0 = srcA[e0], s1 = srcA[e1], s2 = srcA[e2], s3 = srcA[e3];
            float g0 = g[(size_t)s0 * HD + lane];
            float g1 = g[(size_t)s1 * HD + lane];
            float g2 = g[(size_t)s2 * HD + lane];
            float g3 = g[(size_t)s3 * HD + lane];
            acc = fmaf(ew[e0], g0, acc);
            acc = fmaf(ew[e1], g1, acc);
            acc = fmaf(ew[e2], g2, acc);
            acc = fmaf(ew[e3], g3, acc);
        }
    }
    // scalar tail
    for (; p < pe; ++p) {
        if (FULL) {
            int2 v = pairsS[p];
            acc = fmaf(__int_as_float(v.y),
                       g[(size_t)(v.x & 0x1FFFF) * HD + lane], acc);
        } else {
            int e = eid[p];
            acc = fmaf(ew[e], g[(size_t)srcA[e] * HD + lane], acc);
        }
    }
    agg[(size_t)row * HD + lane] = di * acc;
}

// ---------------------------------------------------------------------------
// GEMM1: x[N,256] @ W1[256,64]. 64 rows/block, 64 THREADS (one wave),
// thread tile 8 rows x 8 cols (rs=tid>>3, cg=tid&7) = 16 FMA per b128
// (R15's 4x8 was 10.7 -> 2.4M wave-b128 = 47 µs DS-issue; this is 1.6M).
// Grid 1563 = 6.1 waves/CU; 1-wave blocks make barriers ~free and stage
// stalls overlap at block granularity. Staging: thread t loads row base+t
// (64 distinct lines per instr). K chunked by 32.
// SCALE: multiply output row by dinv[row] (g-space).
// ---------------------------------------------------------------------------
template <bool SCALE>
__global__ __launch_bounds__(64, 2) void k_gemm1(const float* __restrict__ x,
                                                 const float* __restrict__ W1,
                                                 const float* __restrict__ dinv,
                                                 float* __restrict__ h0) {
    __shared__ float sX[32][68];     // [k][row], padded (8.7 KB)
    __shared__ float sW[32][64];     // [k][col] (8 KB)
    int tid = threadIdx.x;           // 0..63
    int rs  = tid >> 3;              // 0..7: row octet (8 rows each)
    int cg  = tid & 7;               // 0..7: col octet (8 cols each)
    int base = blockIdx.x * 64;

    int growc = (base + tid < NN) ? (base + tid) : (NN - 1);

    float acc[8][8];
#pragma unroll
    for (int r = 0; r < 8; ++r)
#pragma unroll
        for (int c = 0; c < 8; ++c) acc[r][c] = 0.0f;

    for (int kc = 0; kc < IN_F; kc += 32) {
        __syncthreads();
        // stage W chunk: rows kc..kc+31 of W1 = 8 KB = 512 f4
        {
            const float4* wsrc = (const float4*)(W1 + (size_t)kc * HD);
            float4* wdst = (float4*)&sW[0][0];
#pragma unroll
            for (int q = 0; q < 8; ++q) wdst[q * 64 + tid] = wsrc[q * 64 + tid];
        }
        // stage x chunk k-major: thread t loads ITS row (base+t), all 32 k
#pragma unroll
        for (int q2 = 0; q2 < 8; ++q2) {
            int koff = q2 * 4;
            float4 v = *(const float4*)(x + (size_t)growc * IN_F + kc + koff);
            sX[koff + 0][tid] = v.x;
            sX[koff + 1][tid] = v.y;
            sX[koff + 2][tid] = v.z;
            sX[koff + 3][tid] = v.w;
        }
        __syncthreads();
        // compute: per k: 2 b128 x + 2 b128 W + 64 FMA
#pragma unroll 2
        for (int k = 0; k < 32; ++k) {
            float xs[8];
            *(float4*)(xs + 0) = *(const float4*)&sX[k][rs * 8];
            *(float4*)(xs + 4) = *(const float4*)&sX[k][rs * 8 + 4];
            float wv[8];
            *(float4*)(wv + 0) = *(const float4*)&sW[k][cg * 8];
            *(float4*)(wv + 4) = *(const float4*)&sW[k][cg * 8 + 4];
#pragma unroll
            for (int r = 0; r < 8; ++r) {
                float xj = xs[r];
#pragma unroll
                for (int c = 0; c < 8; ++c) acc[r][c] = fmaf(xj, wv[c], acc[r][c]);
            }
        }
    }
#pragma unroll
    for (int r = 0; r < 8; ++r) {
        int row = base + rs * 8 + r;
        if (row >= NN) continue;
        float di = SCALE ? dinv[row] : 1.0f;
        float* hp = h0 + (size_t)row * HD + cg * 8;
        *(float4*)(hp + 0) = make_float4(acc[r][0] * di, acc[r][1] * di,
                                         acc[r][2] * di, acc[r][3] * di);
        *(float4*)(hp + 4) = make_float4(acc[r][4] * di, acc[r][5] * di,
                                         acc[r][6] * di, acc[r][7] * di);
    }
}

// ---------------------------------------------------------------------------
// 64x64 GEMM, LDS-staged both operands, input bias+relu fused into staging
// (R15, measured win). 64 rows/block, 256 threads, 4x4 tile.
// BIASRELU: output += bout, relu. SCALEOUT: output row *= dinv[row].
// ---------------------------------------------------------------------------
template <bool BIASRELU, bool SCALEOUT>
__global__ __launch_bounds__(256, 4) void k_gemm64(const float* __restrict__ in,
                                                   const float* __restrict__ bin,
                                                   const float* __restrict__ W,
                                                   const float* __restrict__ bout,
                                                   const float* __restrict__ dinv,
                                                   float* __restrict__ outA) {
    __shared__ float sIn[64][68];    // relu(in+bin), k-major (17.4 KB)
    __shared__ float sW[64][64];     // (16 KB)
    int tid = threadIdx.x;
    int rs  = tid >> 4;              // 0..15: row group (4 rows each)
    int cg  = tid & 15;              // 0..15: col group (4 cols each)
    int base = blockIdx.x * 64;
    int f4   = tid >> 5;             // 0..7
    int srow = tid & 31;

    // stage W: 64x64 = 1024 f4
    {
        const float4* wsrc = (const float4*)W;
        float4* wdst = (float4*)&sW[0][0];
#pragma unroll
        for (int q = 0; q < 4; ++q) wdst[q * 256 + tid] = wsrc[q * 256 + tid];
    }
    // stage in with fused bias+relu, k-major
#pragma unroll
    for (int q2 = 0; q2 < 2; ++q2) {
        int koff = q2 * 32 + f4 * 4;
        float4 bb = *(const float4*)(bin + koff);
#pragma unroll
        for (int q = 0; q < 2; ++q) {
            int grow = q * 32 + srow;
            int growc = (base + grow < NN) ? (base + grow) : (NN - 1);
            float4 v = *(const float4*)(in + (size_t)growc * HD + koff);
            sIn[koff + 0][grow] = fmaxf(v.x + bb.x, 0.0f);
            sIn[koff + 1][grow] = fmaxf(v.y + bb.y, 0.0f);
            sIn[koff + 2][grow] = fmaxf(v.z + bb.z, 0.0f);
            sIn[koff + 3][grow] = fmaxf(v.w + bb.w, 0.0f);
        }
    }
    __syncthreads();

    float acc[4][4];
#pragma unroll
    for (int r = 0; r < 4; ++r)
#pragma unroll
        for (int c = 0; c < 4; ++c) acc[r][c] = 0.0f;

#pragma unroll 4
    for (int k = 0; k < HD; ++k) {
        float xs[4];
        *(float4*)xs = *(const float4*)&sIn[k][rs * 4];
        float wv[4];
        *(float4*)wv = *(const float4*)&sW[k][cg * 4];
#pragma unroll
        for (int r = 0; r < 4; ++r) {
            float hv = xs[r];
#pragma unroll
            for (int c = 0; c < 4; ++c) acc[r][c] = fmaf(hv, wv[c], acc[r][c]);
        }
    }

#pragma unroll
    for (int r = 0; r < 4; ++r) {
        int row = base + rs * 4 + r;
        if (row >= NN) continue;
        float* ha = outA + (size_t)row * HD + cg * 4;
        if (BIASRELU) {
            float bo[4];
            *(float4*)bo = *(const float4*)(bout + cg * 4);
            *(float4*)ha = make_float4(fmaxf(acc[r][0] + bo[0], 0.0f),
                                       fmaxf(acc[r][1] + bo[1], 0.0f),
                                       fmaxf(acc[r][2] + bo[2], 0.0f),
                                       fmaxf(acc[r][3] + bo[3], 0.0f));
        } else {
            float di = SCALEOUT ? dinv[row] : 1.0f;
            *(float4*)ha = make_float4(acc[r][0] * di, acc[r][1] * di,
                                       acc[r][2] * di, acc[r][3] * di);
        }
    }
}

// --- fallback path kernels ---
__global__ __launch_bounds__(256) void k_init_fb(float* __restrict__ deg) {
    int i = blockIdx.x * 256 + threadIdx.x;
    if (i < NN) deg[i] = 1.0f;
}
__global__ __launch_bounds__(256) void k_edge_fb(const int* __restrict__ dst,
                                                 const float* __restrict__ ew,
                                                 float* __restrict__ deg) {
    int e = blockIdx.x * 256 + threadIdx.x;
    if (e < NE) atomicAdd(&deg[dst[e]], ew[e]);
}
__global__ __launch_bounds__(256) void k_dinv_fb(float* __restrict__ deg) {
    int i = blockIdx.x * 256 + threadIdx.x;
    if (i < NN) {
        float d = deg[i];
        deg[i] = d > 0.0f ? rsqrtf(d) : 0.0f;
    }
}
__global__ __launch_bounds__(256) void k_selfloop(const float* __restrict__ h,
                                                  const float* __restrict__ dinv,
                                                  float* __restrict__ agg) {
    int i = blockIdx.x * 256 + threadIdx.x;
    if (i >= NN * (HD / 4)) return;
    int row = i / (HD / 4);
    float di = dinv[row];
    float d2 = di * di;
    float4 v = ((const float4*)h)[i];
    ((float4*)agg)[i] = make_float4(v.x * d2, v.y * d2, v.z * d2, v.w * d2);
}
__global__ __launch_bounds__(256) void k_scatter(const int* __restrict__ src,
                                                 const int* __restrict__ dst,
                                                 const float* __restrict__ ew,
                                                 const float* __restrict__ dinv,
                                                 const float* __restrict__ h,
                                                 float* __restrict__ agg) {
    int e = blockIdx.x * 4 + (threadIdx.x >> 6);
    int lane = threadIdx.x & 63;
    if (e >= NE) return;
    int s = src[e];
    int d = dst[e];
    float nrm = dinv[s] * ew[e] * dinv[d];
    float v = h[(size_t)s * HD + lane] * nrm;
    atomicAdd(&agg[(size_t)d * HD + lane], v);
}

// logits = h3 @ Wm2 + bm2, softmax. Wm2 (4 KB) in LDS, 1 row/thread (grid 391).
__global__ __launch_bounds__(256, 4) void k_out(const float* __restrict__ h3,
                                                const float* __restrict__ Wm2,
                                                const float* __restrict__ bm2,
                                                float* __restrict__ out) {
    __shared__ float sW[HD * NC];
    int tid = threadIdx.x;
    ((float4*)sW)[tid] = ((const float4*)Wm2)[tid];
    __syncthreads();
    int row = blockIdx.x * 256 + tid;
    bool rv = row < NN;
    int rowc = rv ? row : (NN - 1);
    float acc[16];
#pragma unroll
    for (int c = 0; c < 16; ++c) acc[c] = 0.0f;

    for (int k4 = 0; k4 < 16; ++k4) {
        float xs[4];
        *(float4*)xs = *(const float4*)(h3 + (size_t)rowc * HD + k4 * 4);
#pragma unroll
        for (int j = 0; j < 4; ++j) {
            float wv[16];
            const float4* wr4 = (const float4*)(sW + (k4 * 4 + j) * NC);
#pragma unroll
            for (int q = 0; q < 4; ++q) ((float4*)wv)[q] = wr4[q];
            float xj = xs[j];
#pragma unroll
            for (int c = 0; c < 16; ++c) acc[c] = fmaf(xj, wv[c], acc[c]);
        }
    }
    if (!rv) return;
    float bm[16];
#pragma unroll
    for (int q = 0; q < 4; ++q) ((float4*)bm)[q] = ((const float4*)bm2)[q];
    float l[16];
#pragma unroll
    for (int c = 0; c < 16; ++c) l[c] = acc[c] + bm[c];
    float m = l[0];
#pragma unroll
    for (int c = 1; c < 16; ++c) m = fmaxf(m, l[c]);
    float ssum = 0.0f;
#pragma unroll
    for (int c = 0; c < 16; ++c) {
        l[c] = expf(l[c] - m);
        ssum += l[c];
    }
    float inv = 1.0f / ssum;
    float4* op = (float4*)(out + (size_t)rowc * NC);
#pragma unroll
    for (int q = 0; q < 4; ++q)
        op[q] = make_float4(l[q * 4] * inv, l[q * 4 + 1] * inv,
                            l[q * 4 + 2] * inv, l[q * 4 + 3] * inv);
}

extern "C" void kernel_launch(void* const* d_in, const int* in_sizes, int n_in,
                              void* d_out, int out_size, void* d_ws, size_t ws_size,
                              hipStream_t stream) {
    const float* x   = (const float*)d_in[0];
    const int*   ei  = (const int*)d_in[1];   // (2, E): [0,E)=src, [E,2E)=dst
    const float* ew  = (const float*)d_in[2];
    const float* W1  = (const float*)d_in[3];
    const float* b1  = (const float*)d_in[4];
    const float* W2  = (const float*)d_in[5];
    const float* b2  = (const float*)d_in[6];
    const float* Wm1 = (const float*)d_in[7];
    const float* bm1 = (const float*)d_in[8];
    const float* Wm2 = (const float*)d_in[9];
    const float* bm2 = (const float*)d_in[10];
    float* out = (float*)d_out;

    char* base = (char*)d_ws;
    float* dinv   = (float*)base;
    float* A      = (float*)(base + 400128);
    float* B      = (float*)(base + 26000128);
    int*   rowptr = (int*)(base + 51600128);        // (NN+1) ints
    int2*  pairsS = (int2*)(base + 52000256);       // FULL only
    // temporaries aliasing A / B before they're live:
    int2*  tmp    = (int2*)(base + 400128);         // in A, dead after k_sort
    int*   counts = (int*)(base + 26000128);        // CM ints = 1.23 MB
    int*   bsum   = (int*)(base + 26000128 + 1226176);
    int*   bpref  = (int*)(base + 26000128 + 1227376);

    const int* src = ei;
    const int* dst = ei + NE;

    const bool full  = ws_size >= (size_t)64800912;
    const bool douta = !full && ws_size >= (size_t)52000912;
    const int g_node = (NN + 255) / 256;   // 391
    const int g_g1   = (NN + 63) / 64;     // 1563 (64-thread blocks)
    const int g_g64  = (NN + 63) / 64;     // 1563
    const int g_agg  = (NN + 3) / 4;       // 25000
    const int g_red  = (NN * (HD / 4) + 255) / 256;  // 6250
    const int g_out  = (NN + 255) / 256;   // 391
    int* eid = (int*)d_out;

    if (full || douta) {
        // bucket build (LDS int atomics only)
        k_count<<<dim3(NBLK), dim3(256), 0, stream>>>(dst, counts);
        k_scan1<<<dim3(SCB), dim3(256), 0, stream>>>(counts, bsum);
        k_scan2<<<dim3(1), dim3(512), 0, stream>>>(bsum, bpref);
        k_scan3<<<dim3((CM + 255) / 256), dim3(256), 0, stream>>>(counts, bpref);
        if (full) {
            k_fill2<true><<<dim3(NBLK), dim3(256), 0, stream>>>(src, dst, ew, counts, tmp);
            k_sort<true><<<dim3(NT), dim3(256), 0, stream>>>(counts, tmp, pairsS, nullptr, rowptr, ew, dinv);
        } else {
            k_fill2<false><<<dim3(NBLK), dim3(256), 0, stream>>>(src, dst, ew, counts, tmp);
            k_sort<false><<<dim3(NT), dim3(256), 0, stream>>>(counts, tmp, nullptr, eid, rowptr, ew, dinv);
        }
        // layer 1: g1 = dinv .* (x @ W1)  (tmp dead -> A writable)
        k_gemm1<true><<<dim3(g_g1), dim3(64), 0, stream>>>(x, W1, dinv, A);
        if (full)
            k_agg<true><<<dim3(g_agg), dim3(256), 0, stream>>>(rowptr, pairsS, nullptr, src, ew, dinv, A, B);
        else
            k_agg<false><<<dim3(g_agg), dim3(256), 0, stream>>>(rowptr, nullptr, eid, src, ew, dinv, A, B);
        // layer 2: g2 = dinv .* (relu(agg1+b1) @ W2)
        k_gemm64<false, true><<<dim3(g_g64), dim3(256), 0, stream>>>(B, b1, W2, nullptr, dinv, A);
        if (full)
            k_agg<true><<<dim3(g_agg), dim3(256), 0, stream>>>(rowptr, pairsS, nullptr, src, ew, dinv, A, B);
        else
            k_agg<false><<<dim3(g_agg), dim3(256), 0, stream>>>(rowptr, nullptr, eid, src, ew, dinv, A, B);
        // MLP head + softmax (no scaling)
        k_gemm64<true, false><<<dim3(g_g64), dim3(256), 0, stream>>>(B, b2, Wm1, bm1, dinv, A);
        k_out<<<dim3(g_out), dim3(256), 0, stream>>>(A, Wm2, bm2, out);
    } else {
        // fallback: atomic scatter (h-space, unscaled producers)
        k_init_fb<<<dim3(g_node), dim3(256), 0, stream>>>(dinv);
        k_edge_fb<<<dim3(NE / 256), dim3(256), 0, stream>>>(dst, ew, dinv);
        k_dinv_fb<<<dim3(g_node), dim3(256), 0, stream>>>(dinv);
        k_gemm1<false><<<dim3(g_g1), dim3(64), 0, stream>>>(x, W1, dinv, A);
        k_selfloop<<<dim3(g_red), dim3(256), 0, stream>>>(A, dinv, B);
        k_scatter<<<dim3(NE / 4), dim3(256), 0, stream>>>(src, dst, ew, dinv, A, B);
        k_gemm64<false, false><<<dim3(g_g64), dim3(256), 0, stream>>>(B, b1, W2, nullptr, dinv, A);
        k_selfloop<<<dim3(g_red), dim3(256), 0, stream>>>(A, dinv, B);
        k_scatter<<<dim3(NE / 4), dim3(256), 0, stream>>>(src, dst, ew, dinv, A, B);
        k_gemm64<true, false><<<dim3(g_g64), dim3(256), 0, stream>>>(B, b2, Wm1, bm1, dinv, A);
        k_out<<<dim3(g_out), dim3(256), 0, stream>>>(A, Wm2, bm2, out);
    }
}